// Round 8
// baseline (9840.187 us; speedup 1.0000x reference)
//
#include <hip/hip_runtime.h>
#include <hip/hip_bf16.h>
#include <cstddef>

// Problem constants
#define VOCAB 50000
#define D_EMB 512
#define HDIM  512
#define MDIM  512
#define BATCH 1024
#define SEQL  64
#define ROWS  2048          // 2 inputs * BATCH
#define HC_K  3136          // 3073 padded to 49*64
#define NBLK  256           // persistent blocks: 8 bx * 16 by * 2 dir

typedef _Float16 f16;
typedef __attribute__((ext_vector_type(8))) _Float16 f16x8;
typedef __attribute__((ext_vector_type(4))) float f32x4;
typedef unsigned long long u64;

__device__ __forceinline__ float sigf(float x) {
    return 1.0f / (1.0f + __expf(-x));
}
__device__ __forceinline__ float tanh_fast(float x) {
    x = fminf(30.0f, fmaxf(-30.0f, x));
    float t = __expf(-2.0f * x);
    return (1.0f - t) / (1.0f + t);
}
__device__ __forceinline__ void glds16(const void* g, const void* lds) {
    __builtin_amdgcn_global_load_lds(
        (const __attribute__((address_space(1))) unsigned int*)g,
        (__attribute__((address_space(3))) unsigned int*)lds, 16, 0, 0);
}

// ---------------------------------------------------------------------------
// fp32 -> fp16 embedding convert
// ---------------------------------------------------------------------------
__global__ __launch_bounds__(256) void conv_emb(const float* __restrict__ src,
                                                f16* __restrict__ dst, int n8) {
    int i = blockIdx.x * 256 + threadIdx.x;
    if (i >= n8) return;
    const float4* s = (const float4*)src + (size_t)i * 2;
    float4 a = s[0], b = s[1];
    f16x8 o = {(f16)a.x, (f16)a.y, (f16)a.z, (f16)a.w,
               (f16)b.x, (f16)b.y, (f16)b.z, (f16)b.w};
    *(f16x8*)&dst[(size_t)i * 8] = o;
}

// ---------------------------------------------------------------------------
// Pack LSTM weights: Wt[dir][col'][k] (fp16), k = [Wx(512);Wh(512)]
// col' = 64*(n>>4) + g*16 + (n&15)
// ---------------------------------------------------------------------------
__global__ __launch_bounds__(256) void pack_w(const float* __restrict__ kfw,
                                              const float* __restrict__ kbw,
                                              f16* __restrict__ Wt) {
    unsigned idx = blockIdx.x * 256 + threadIdx.x;   // over 2*2048*1024
    int k    = idx & 1023;
    int colp = (idx >> 10) & 2047;
    int d    = idx >> 21;
    int cg = colp >> 6, g = (colp >> 4) & 3, ci = colp & 15;
    int n = cg * 16 + ci;
    const float* K = d ? kbw : kfw;
    Wt[idx] = (f16)K[(size_t)k * 2048 + g * 512 + n];
}

// ---------------------------------------------------------------------------
// Pack W1: W1t[col][k] fp16, k padded 3073 -> 3136
// ---------------------------------------------------------------------------
__global__ __launch_bounds__(256) void pack_w1(const float* __restrict__ W1,
                                               f16* __restrict__ W1t) {
    int idx = blockIdx.x * 256 + threadIdx.x;
    if (idx >= 512 * HC_K) return;
    int k = idx % HC_K, c = idx / HC_K;
    W1t[idx] = (k < 3073) ? (f16)W1[(size_t)k * MDIM + c] : (f16)0.0f;
}

// ---------------------------------------------------------------------------
// Deterministic rank-sort by seqlen DESC (tie: original index asc).
// ---------------------------------------------------------------------------
__global__ __launch_bounds__(256) void sort_rows(const int* __restrict__ sl1,
                                                 const int* __restrict__ sl2,
                                                 int* __restrict__ perm,
                                                 int* __restrict__ inv,
                                                 int* __restrict__ Acnt) {
    __shared__ int s_sh[ROWS];
    int tid = threadIdx.x;
    for (int i = tid; i < ROWS; i += 256) {
        int b = i & (BATCH - 1);
        s_sh[i] = (i < BATCH) ? sl1[b] : sl2[b];
    }
    __syncthreads();
    int i = blockIdx.x * 256 + tid;
    int key = (s_sh[i] << 12) - i;
    int rank = 0;
#pragma unroll 4
    for (int j = 0; j < ROWS; j += 4) {
        int4 v = *(const int4*)&s_sh[j];
        rank += ((v.x << 12) - (j + 0)) > key;
        rank += ((v.y << 12) - (j + 1)) > key;
        rank += ((v.z << 12) - (j + 2)) > key;
        rank += ((v.w << 12) - (j + 3)) > key;
    }
    perm[rank] = i;
    inv[i] = rank;
    if (blockIdx.x == 0 && tid < SEQL) {
        int c = 0;
#pragma unroll 4
        for (int j = 0; j < ROWS; j += 4) {
            int4 v = *(const int4*)&s_sh[j];
            c += (v.x > tid) + (v.y > tid) + (v.z > tid) + (v.w > tid);
        }
        Acnt[tid] = c;
    }
}

// ---------------------------------------------------------------------------
// MFMA on one staged k-tile: M=128, N=256, 8 waves (2 wr x 4 wc).
// ---------------------------------------------------------------------------
__device__ __forceinline__ void mma_tile(const f16* At, const f16* Bt,
                                         int l, int wr, int wc,
                                         f32x4 (&acc)[4][4]) {
#pragma unroll
    for (int kk = 0; kk < 2; ++kk) {
        f16x8 af[4], bv[4];
        const int slot = (l >> 4) + kk * 4;
#pragma unroll
        for (int fm = 0; fm < 4; ++fm) {
            int row = wr * 64 + fm * 16 + (l & 15);
            af[fm] = *(const f16x8*)&At[row * 64 + ((slot ^ (row & 7)) << 3)];
        }
#pragma unroll
        for (int fn = 0; fn < 4; ++fn) {
            int col = wc * 64 + fn * 16 + (l & 15);
            bv[fn] = *(const f16x8*)&Bt[col * 64 + ((slot ^ (col & 7)) << 3)];
        }
#pragma unroll
        for (int fm = 0; fm < 4; ++fm)
#pragma unroll
            for (int fn = 0; fn < 4; ++fn)
                acc[fm][fn] = __builtin_amdgcn_mfma_f32_16x16x32_f16(
                    af[fm], bv[fn], acc[fm][fn], 0, 0, 0);
    }
}

// ---------------------------------------------------------------------------
// x-part GEMM (K 0..511): embedding gather via glds16, classic dbuf.
// ---------------------------------------------------------------------------
__device__ __forceinline__ void gemm_x(const f16* __restrict__ embB,
                                       const int aoffX[2],
                                       const f16* __restrict__ Wt,
                                       const size_t boffX[4],
                                       const int dstA[2], const int dstB[4],
                                       int l, int wr, int wc,
                                       f16 (*At)[8192], f16 (*Bt)[16384],
                                       f32x4 (&acc)[4][4]) {
#pragma unroll
    for (int g = 0; g < 2; ++g) glds16(embB + aoffX[g], &At[0][dstA[g]]);
#pragma unroll
    for (int r = 0; r < 4; ++r) glds16(Wt + boffX[r], &Bt[0][dstB[r]]);
    __syncthreads();
#pragma unroll
    for (int kt = 0; kt < 8; ++kt) {
        const int cur = kt & 1;
        if (kt < 7) {
#pragma unroll
            for (int g = 0; g < 2; ++g)
                glds16(embB + aoffX[g] + (kt + 1) * 64, &At[cur ^ 1][dstA[g]]);
#pragma unroll
            for (int r = 0; r < 4; ++r)
                glds16(Wt + boffX[r] + (kt + 1) * 64, &Bt[cur ^ 1][dstB[r]]);
        }
        mma_tile(At[cur], Bt[cur], l, wr, wc, acc);
        __syncthreads();
    }
}

// ---------------------------------------------------------------------------
// h-part GEMM (K 512..1023): h loaded with AGENT-scope atomic u64 (coherent
// across XCDs by construction), staged to LDS via ds_write_b64 (swizzled).
// B prefetched via glds16 dbuf; mid-loop barrier waits lgkmcnt only.
// ---------------------------------------------------------------------------
__device__ __forceinline__ void gemm_h(const f16* __restrict__ hin,
                                       size_t habase,         // f16 idx of (dir,by) row0
                                       const f16* __restrict__ Wt,
                                       const size_t boffH[4],
                                       const int dstB[4],
                                       int tid, int l, int wr, int wc,
                                       f16* At0, f16 (*Bt)[16384],
                                       f32x4 (&acc)[4][4]) {
    const int kc = tid & 15;          // 4-f16 granule within 64-wide k-tile
    const int r0 = tid >> 4;          // row base (stride 32 over j)
    u64 ra[4], rb[4];
#pragma unroll
    for (int j = 0; j < 4; ++j) {
        int row = r0 + j * 32;
        ra[j] = __hip_atomic_load(
            (const u64*)(hin + habase + ((size_t)row << 9) + kc * 4),
            __ATOMIC_RELAXED, __HIP_MEMORY_SCOPE_AGENT);
    }
#pragma unroll
    for (int r = 0; r < 4; ++r) glds16(Wt + boffH[r], &Bt[0][dstB[r]]);

#pragma unroll
    for (int kt = 0; kt < 8; ++kt) {
        const int cur = kt & 1;
        asm volatile("s_waitcnt vmcnt(0)" ::: "memory");
        __builtin_amdgcn_s_barrier();       // prev compute done; At0 free
#pragma unroll
        for (int j = 0; j < 4; ++j) {
            int row = r0 + j * 32;
            *(u64*)&At0[row * 64 + (((kc >> 1) ^ (row & 7)) << 3) + (kc & 1) * 4] =
                (kt & 1) ? rb[j] : ra[j];
        }
        if (kt < 7) {
#pragma unroll
            for (int j = 0; j < 4; ++j) {
                int row = r0 + j * 32;
                u64 v = __hip_atomic_load(
                    (const u64*)(hin + habase + ((size_t)row << 9) +
                                 (kt + 1) * 64 + kc * 4),
                    __ATOMIC_RELAXED, __HIP_MEMORY_SCOPE_AGENT);
                if (kt & 1) ra[j] = v; else rb[j] = v;
            }
#pragma unroll
            for (int r = 0; r < 4; ++r)
                glds16(Wt + boffH[r] + (kt + 1) * 64, &Bt[cur ^ 1][dstB[r]]);
        }
        asm volatile("s_waitcnt lgkmcnt(0)" ::: "memory");
        __builtin_amdgcn_sched_barrier(0);
        __builtin_amdgcn_s_barrier();       // At0 writes visible
        mma_tile(At0, Bt[cur], l, wr, wc, acc);
    }
}

// ---------------------------------------------------------------------------
// Persistent cooperative LSTM: all 64 steps, one dispatch.
// 256 blocks x 512 threads (1/CU). Block: (bx 0..7)x(by 0..15)x(dir 0..1);
// per step: h-GEMM(t) + epilogue (c in regs, h u32 atomic stores) -> arrive
// -> x-GEMM(t+1) overlapping the epoch wait -> wait.
// ---------------------------------------------------------------------------
__global__ __launch_bounds__(512, 2) void lstm_all(
    const int* __restrict__ in1, const int* __restrict__ in2,
    const int* __restrict__ sl1, const int* __restrict__ sl2,
    const int* __restrict__ perm, const int* __restrict__ Acnt,
    const f16* __restrict__ embH, const f16* __restrict__ Wt,
    const float* __restrict__ bfw, const float* __restrict__ bbw,
    f16* __restrict__ hb0, f16* __restrict__ hb1,
    int* __restrict__ scnt) {
    const int tid = threadIdx.x;
    const int l = tid & 63, w = tid >> 6;
    const int bid = blockIdx.x;
    const int grp  = bid & 7;                   // sync group (and L2 locality)
    const int slot = (bid >> 3) & 1;
    const int by   = bid >> 4;                  // row tile 0..15
    const int p    = grp * 2 + slot;            // 0..15
    const int bx   = p >> 1;                    // col tile 0..7 (256 cols)
    const int dir  = p & 1;

    __shared__ f16 At[2][8192];      // 32 KB (x dbuf; At[0] reused by h)
    __shared__ f16 Bt[2][16384];     // 64 KB
    __shared__ int toks[128];
    __shared__ int slens[128];
    __shared__ int acs[SEQL];

    int myb = 0, mys = 0;
    const int* myinp = in1;
    if (tid < 128) {
        int r = perm[by * 128 + tid];
        myb = r & (BATCH - 1);
        myinp = (r < BATCH) ? in1 : in2;
        mys = (r < BATCH) ? sl1[myb] : sl2[myb];
        slens[tid] = mys;
        int tt0 = dir ? (mys - 1) : 0;          // t=0 active for all (s>=1)
        toks[tid] = myinp[myb * SEQL + tt0];
    }
    if (tid < SEQL) acs[tid] = Acnt[tid];
    __syncthreads();

    // ---- constant staging descriptors
    const int kg8 = (((l & 7) ^ ((l >> 3) & 7))) * 8;
    int dstA[2]; size_t boffX[4], boffH[4]; int dstB[4];
#pragma unroll
    for (int g = 0; g < 2; ++g) dstA[g] = (tid + g * 512) * 8;
#pragma unroll
    for (int r = 0; r < 4; ++r) {
        int col = (tid >> 3) + r * 64;          // 0..255
        boffX[r] = ((size_t)(dir * 2048 + bx * 256 + col) << 10) + kg8;
        boffH[r] = boffX[r] + 512;
        dstB[r]  = (tid + r * 512) * 8;
    }
    const int wr = w >> 2, wc = w & 3;
    const size_t habase = (size_t)(dir * ROWS + by * 128) << 9;

    const float* bias = dir ? bbw : bfw;
    const int ci = l & 15;
    const int cell = (bx * 4 + wc) * 16 + ci;   // 0..511
    float bg[4];
#pragma unroll
    for (int g = 0; g < 4; ++g) bg[g] = bias[g * 512 + cell];

    float creg[4][4];
#pragma unroll
    for (int i = 0; i < 4; ++i)
#pragma unroll
        for (int j = 0; j < 4; ++j) creg[i][j] = 0.0f;

    f32x4 accA[4][4], accB[4][4];
#pragma unroll
    for (int i = 0; i < 4; ++i)
#pragma unroll
        for (int j = 0; j < 4; ++j) accA[i][j] = (f32x4){0.f, 0.f, 0.f, 0.f};

    // prologue: x-part of t=0 into accA
    {
        int ax[2];
#pragma unroll
        for (int g = 0; g < 2; ++g)
            ax[g] = toks[(tid >> 3) + g * 64] * 512 + kg8;
        gemm_x(embH, ax, Wt, boffX, dstA, dstB, l, wr, wc, At, Bt, accA);
    }

#define STEP_BODY(T, ACCC, ACCN)                                               \
    {                                                                          \
        const int t_ = (T);                                                    \
        const f16* hin = (t_ & 1) ? hb1 : hb0;                                 \
        f16* hout      = (t_ & 1) ? hb0 : hb1;                                 \
        if (by * 128 < acs[t_]) {                                              \
            gemm_h(hin, habase, Wt, boffH, dstB, tid, l, wr, wc,               \
                   At[0], Bt, ACCC);                                           \
            _Pragma("unroll") for (int fm = 0; fm < 4; ++fm) {                 \
                _Pragma("unroll") for (int reg = 0; reg < 4; ++reg) {          \
                    int rl = wr * 64 + fm * 16 + (l >> 4) * 4 + reg;           \
                    float gi = ACCC[fm][0][reg] + bg[0];                       \
                    float gj = ACCC[fm][1][reg] + bg[1];                       \
                    float gf = ACCC[fm][2][reg] + bg[2];                       \
                    float go = ACCC[fm][3][reg] + bg[3];                       \
                    float cn = creg[fm][reg] * sigf(gf + 1.0f)                 \
                             + sigf(gi) * tanh_fast(gj);                       \
                    float hn = tanh_fast(cn) * sigf(go);                       \
                    f16 hf = (f16)hn;                                          \
                    unsigned hv = *(unsigned short*)&hf;                       \
                    unsigned ov = (unsigned)__shfl_xor((int)hv, 1);            \
                    if (t_ < slens[rl]) {                                      \
                        creg[fm][reg] = cn;                                    \
                        if ((l & 1) == 0) {                                    \
                            unsigned pk = hv | (ov << 16);                     \
                            __hip_atomic_store(                                \
                                (unsigned*)(hout + habase +                    \
                                            ((size_t)rl << 9) + cell),         \
                                pk, __ATOMIC_RELAXED,                          \
                                __HIP_MEMORY_SCOPE_AGENT);                     \
                        }                                                      \
                    }                                                          \
                }                                                              \
            }                                                                  \
        }                                                                      \
        if (t_ < SEQL - 1) {                                                   \
            __syncthreads();   /* drains vmcnt: h stores complete */           \
            if (tid == 0) {                                                    \
                __builtin_amdgcn_fence(__ATOMIC_RELEASE, "agent");             \
                int old = __hip_atomic_fetch_add(&scnt[grp << 4], 1,           \
                    __ATOMIC_ACQ_REL, __HIP_MEMORY_SCOPE_AGENT);               \
                if (old == 32 * (t_ + 1) - 1) {                                \
                    int m = __hip_atomic_fetch_add(&scnt[128], 1,              \
                        __ATOMIC_ACQ_REL, __HIP_MEMORY_SCOPE_AGENT);           \
                    if (m == 8 * (t_ + 1) - 1)                                 \
                        __hip_atomic_store(&scnt[144], t_ + 1,                 \
                                           __ATOMIC_RELEASE,                   \
                                           __HIP_MEMORY_SCOPE_AGENT);          \
                }                                                              \
            }                                                                  \
            if (tid < 128) {                                                   \
                int t1 = t_ + 1;                                               \
                int tt = dir ? ((t1 < mys) ? (mys - 1 - t1) : t1) : t1;        \
                toks[tid] = myinp[myb * SEQL + tt];                            \
            }                                                                  \
            _Pragma("unroll") for (int i_ = 0; i_ < 4; ++i_)                   \
                _Pragma("unroll") for (int j_ = 0; j_ < 4; ++j_)               \
                    ACCN[i_][j_] = (f32x4){0.f, 0.f, 0.f, 0.f};                \
            __syncthreads();                                                   \
            if (by * 128 < acs[t_ + 1]) {                                      \
                int ax[2];                                                     \
                _Pragma("unroll") for (int g = 0; g < 2; ++g)                  \
                    ax[g] = toks[(tid >> 3) + g * 64] * 512 + kg8;             \
                gemm_x(embH, ax, Wt, boffX, dstA, dstB, l, wr, wc,             \
                       At, Bt, ACCN);                                          \
            }                                                                  \
            if (tid == 0) {                                                    \
                while (__hip_atomic_load(&scnt[144], __ATOMIC_ACQUIRE,         \
                                         __HIP_MEMORY_SCOPE_AGENT) < t_ + 1)   \
                    __builtin_amdgcn_s_sleep(2);                               \
            }                                                                  \
            __syncthreads();                                                   \
            __builtin_amdgcn_fence(__ATOMIC_ACQUIRE, "agent");                 \
        }                                                                      \
    }

#pragma unroll 1
    for (int tp = 0; tp < SEQL / 2; ++tp) {
        STEP_BODY(2 * tp, accA, accB)
        STEP_BODY(2 * tp + 1, accB, accA)
    }
#undef STEP_BODY
}

// ---------------------------------------------------------------------------
// Build h_combined fp16 [1024][3136]; final h of row r in buf[s&1], row inv[r].
// ---------------------------------------------------------------------------
__global__ __launch_bounds__(256) void build_hc(const f16* __restrict__ hbuf0,
                                                const f16* __restrict__ hbuf1,
                                                const int* __restrict__ sl1,
                                                const int* __restrict__ sl2,
                                                const int* __restrict__ inv,
                                                f16* __restrict__ hc) {
    int b = blockIdx.x;
    int tid = threadIdx.x;
    __shared__ float red[256];
    int s1 = sl1[b], s2 = sl2[b];
    int p1 = inv[b], p2 = inv[BATCH + b];
    const f16* hf1 = (s1 & 1) ? hbuf1 : hbuf0;
    const f16* hf2 = (s2 & 1) ? hbuf1 : hbuf0;
    float d = 0.0f;
    size_t base = (size_t)b * HC_K;
    for (int k = tid; k < 1024; k += 256) {
        int dir = k >> 9, kk = k & 511;
        float h1 = (float)hf1[((size_t)(dir * ROWS + p1) << 9) + kk];
        float h2 = (float)hf2[((size_t)(dir * ROWS + p2) << 9) + kk];
        hc[base + k]        = (f16)h1;
        hc[base + 1024 + k] = (f16)h2;
        hc[base + 2049 + k] = (f16)(h1 * h2);
        float df = h1 - h2;
        d += df * df;
    }
    red[tid] = d;
    __syncthreads();
    for (int s = 128; s > 0; s >>= 1) {
        if (tid < s) red[tid] += red[tid + s];
        __syncthreads();
    }
    if (tid == 0) hc[base + 2048] = (f16)red[0];
    if (tid < HC_K - 3073) hc[base + 3073 + tid] = (f16)0.0f;
}

// ---------------------------------------------------------------------------
// e1 = relu(hc @ W1 + b1)  fp16 MFMA 64x64 tile, BK=64, dbuf
// ---------------------------------------------------------------------------
__global__ __launch_bounds__(256) void mlp1(const f16* __restrict__ hc,
                                            const f16* __restrict__ W1t,
                                            const float* __restrict__ b1,
                                            float* __restrict__ e1) {
    const int bx = blockIdx.x, by = blockIdx.y, tid = threadIdx.x;
    const int l = tid & 63, w = tid >> 6;
    __shared__ f16 Atile[2][64 * 64];
    __shared__ f16 Btile[2][64 * 64];

    const int kg8 = (((l & 7) ^ ((l >> 3) & 7))) * 8;
    size_t aoff[2], boff[2]; int dst[2];
#pragma unroll
    for (int g = 0; g < 2; ++g) {
        int row = g * 32 + w * 8 + (l >> 3);
        aoff[g] = (size_t)(by * 64 + row) * HC_K + kg8;
        boff[g] = (size_t)(bx * 64 + row) * HC_K + kg8;
        dst[g]  = (g * 32 + w * 8) * 64;
    }

    f32x4 acc[2][2];
#pragma unroll
    for (int i = 0; i < 2; ++i)
#pragma unroll
        for (int j = 0; j < 2; ++j) acc[i][j] = (f32x4){0.f, 0.f, 0.f, 0.f};

    const int wr = w >> 1, wc = w & 1;

#pragma unroll
    for (int g = 0; g < 2; ++g) {
        glds16(hc + aoff[g], &Atile[0][dst[g]]);
        glds16(W1t + boff[g], &Btile[0][dst[g]]);
    }
    __syncthreads();

    int cur = 0;
    for (int kt = 0; kt < HC_K / 64; ++kt) {
        if (kt < HC_K / 64 - 1) {
            const int kn = (kt + 1) * 64;
#pragma unroll
            for (int g = 0; g < 2; ++g) {
                glds16(hc + aoff[g] + kn, &Atile[cur ^ 1][dst[g]]);
                glds16(W1t + boff[g] + kn, &Btile[cur ^ 1][dst[g]]);
            }
        }
#pragma unroll
        for (int kk = 0; kk < 2; ++kk) {
            f16x8 af[2], bv[2];
            const int slot = (l >> 4) + kk * 4;
#pragma unroll
            for (int fm = 0; fm < 2; ++fm) {
                int row = wr * 32 + fm * 16 + (l & 15);
                af[fm] = *(const f16x8*)&Atile[cur][row * 64 + (slot ^ (row & 7)) * 8];
            }
#pragma unroll
            for (int fn = 0; fn < 2; ++fn) {
                int col = wc * 32 + fn * 16 + (l & 15);
                bv[fn] = *(const f16x8*)&Btile[cur][col * 64 + (slot ^ (col & 7)) * 8];
            }
#pragma unroll
            for (int fm = 0; fm < 2; ++fm)
#pragma unroll
                for (int fn = 0; fn < 2; ++fn)
                    acc[fm][fn] = __builtin_amdgcn_mfma_f32_16x16x32_f16(
                        af[fm], bv[fn], acc[fm][fn], 0, 0, 0);
        }
        __syncthreads();
        cur ^= 1;
    }

#pragma unroll
    for (int fm = 0; fm < 2; ++fm) {
#pragma unroll
        for (int fn = 0; fn < 2; ++fn) {
#pragma unroll
            for (int reg = 0; reg < 4; ++reg) {
                int r = by * 64 + wr * 32 + fm * 16 + (l >> 4) * 4 + reg;
                int c = bx * 64 + wc * 32 + fn * 16 + (l & 15);
                float v = acc[fm][fn][reg] + b1[c];
                e1[(size_t)r * MDIM + c] = v > 0.0f ? v : 0.0f;
            }
        }
    }
}

// ---------------------------------------------------------------------------
// preds = e1 @ W2 + b2
// ---------------------------------------------------------------------------
__global__ __launch_bounds__(64) void mlp2(const float* __restrict__ e1,
                                           const float* __restrict__ W2,
                                           const float* __restrict__ b2,
                                           float* __restrict__ out) {
    int b = blockIdx.x, tid = threadIdx.x;
    float p0 = 0.f, p1 = 0.f;
    for (int k = tid; k < 512; k += 64) {
        float e = e1[(size_t)b * MDIM + k];
        p0 += e * W2[2 * k];
        p1 += e * W2[2 * k + 1];
    }
    for (int off = 32; off > 0; off >>= 1) {
        p0 += __shfl_down(p0, off);
        p1 += __shfl_down(p1, off);
    }
    if (tid == 0) {
        out[2 * b]     = p0 + b2[0];
        out[2 * b + 1] = p1 + b2[1];
    }
}

// ---------------------------------------------------------------------------
extern "C" void kernel_launch(void* const* d_in, const int* in_sizes, int n_in,
                              void* d_out, int out_size, void* d_ws, size_t ws_size,
                              hipStream_t stream) {
    (void)in_sizes; (void)n_in; (void)out_size; (void)ws_size;
    const int*   in1 = (const int*)d_in[0];
    const int*   in2 = (const int*)d_in[1];
    const int*   sl1 = (const int*)d_in[2];
    const int*   sl2 = (const int*)d_in[3];
    const float* emb = (const float*)d_in[4];
    const float* kfw = (const float*)d_in[5];
    const float* bfw = (const float*)d_in[6];
    const float* kbw = (const float*)d_in[7];
    const float* bbw = (const float*)d_in[8];
    const float* W1  = (const float*)d_in[9];
    const float* b1  = (const float*)d_in[10];
    const float* W2  = (const float*)d_in[11];
    const float* b2  = (const float*)d_in[12];
    float* out = (float*)d_out;

    char* base = (char*)d_ws;
    f16*   embH = (f16*)base;                      // 51,200,000 B
    f16*   Wt   = (f16*)(base + 51200000);         //  8,388,608 B
    f16*   W1t  = (f16*)(base + 59588608);         //  3,211,264 B
    f16*   h0   = (f16*)(base + 62799872);         //  4,194,304 B
    f16*   h1   = (f16*)(base + 66994176);         //  4,194,304 B
    f16*   hc   = (f16*)(base + 71188480);         //  6,422,528 B
    float* e1   = (float*)(base + 77611008);       //  2,097,152 B
    int*   perm = (int*)(base + 79708160);         //      8,192 B
    int*   inv  = (int*)(base + 79716352);         //      8,192 B
    int*   Acnt = (int*)(base + 79724544);         //        256 B
    int*   sync = (int*)(base + 79724800);         //      1,024 B

    hipMemsetAsync(h0, 0, 4194304, stream);        // h state at t=0
    hipMemsetAsync(sync, 0, 1024, stream);         // epoch counters

    sort_rows<<<ROWS / 256, 256, 0, stream>>>(sl1, sl2, perm, inv, Acnt);
    conv_emb<<<(VOCAB * D_EMB / 8 + 255) / 256, 256, 0, stream>>>(emb, embH, VOCAB * D_EMB / 8);
    pack_w<<<(2 * 2048 * 1024) / 256, 256, 0, stream>>>(kfw, kbw, Wt);
    pack_w1<<<(512 * HC_K + 255) / 256, 256, 0, stream>>>(W1, W1t);

    {
        const f16* embH_c = embH;
        const f16* Wt_c   = Wt;
        const int* perm_c = perm;
        const int* Acnt_c = Acnt;
        f16* h0_p = h0;
        f16* h1_p = h1;
        int* sync_p = sync;
        void* ka[] = {
            (void*)&in1, (void*)&in2, (void*)&sl1, (void*)&sl2,
            (void*)&perm_c, (void*)&Acnt_c, (void*)&embH_c, (void*)&Wt_c,
            (void*)&bfw, (void*)&bbw, (void*)&h0_p, (void*)&h1_p, (void*)&sync_p
        };
        hipLaunchCooperativeKernel((const void*)lstm_all, dim3(NBLK), dim3(512),
                                   ka, 0, stream);
    }

    build_hc<<<BATCH, 256, 0, stream>>>(h0, h1, sl1, sl2, inv, hc);
    mlp1<<<dim3(MDIM / 64, BATCH / 64), 256, 0, stream>>>(hc, W1t, b1, e1);
    mlp2<<<BATCH, 64, 0, stream>>>(e1, W2, b2, out);
}

// Round 10
// 6980.598 us; speedup vs baseline: 1.4096x; 1.4096x over previous
//
#include <hip/hip_runtime.h>
#include <hip/hip_bf16.h>
#include <cstddef>

// Problem constants
#define VOCAB 50000
#define D_EMB 512
#define HDIM  512
#define MDIM  512
#define BATCH 1024
#define SEQL  64
#define ROWS  2048          // 2 inputs * BATCH
#define HC_K  3136          // 3073 padded to 49*64
#define NBLK  256           // 8 bx * 2 dir * 16 by

typedef _Float16 f16;
typedef __attribute__((ext_vector_type(8))) _Float16 f16x8;
typedef __attribute__((ext_vector_type(4))) float f32x4;

__device__ __forceinline__ float sigf(float x) {
    return 1.0f / (1.0f + __expf(-x));
}
__device__ __forceinline__ float tanh_fast(float x) {
    x = fminf(30.0f, fmaxf(-30.0f, x));
    float t = __expf(-2.0f * x);
    return (1.0f - t) / (1.0f + t);
}
// cached global->LDS (16B/lane)
__device__ __forceinline__ void glds16(const void* g, const void* lds) {
    __builtin_amdgcn_global_load_lds(
        (const __attribute__((address_space(1))) unsigned int*)g,
        (__attribute__((address_space(3))) unsigned int*)lds, 16, 0, 0);
}
// coherent global->LDS: CPol = SC0(1) | SC1(16) = 17 -> bypass L1+L2, read
// the device coherence point (where agent-scope atomic stores land).
__device__ __forceinline__ void glds16c(const void* g, const void* lds) {
    __builtin_amdgcn_global_load_lds(
        (const __attribute__((address_space(1))) unsigned int*)g,
        (__attribute__((address_space(3))) unsigned int*)lds, 16, 0, 17);
}

// ---------------------------------------------------------------------------
// fp32 -> fp16 embedding convert
// ---------------------------------------------------------------------------
__global__ __launch_bounds__(256) void conv_emb(const float* __restrict__ src,
                                                f16* __restrict__ dst, int n8) {
    int i = blockIdx.x * 256 + threadIdx.x;
    if (i >= n8) return;
    const float4* s = (const float4*)src + (size_t)i * 2;
    float4 a = s[0], b = s[1];
    f16x8 o = {(f16)a.x, (f16)a.y, (f16)a.z, (f16)a.w,
               (f16)b.x, (f16)b.y, (f16)b.z, (f16)b.w};
    *(f16x8*)&dst[(size_t)i * 8] = o;
}

// ---------------------------------------------------------------------------
// Pack LSTM weights: Wt[dir][col'][k] (fp16), k = [Wx(512);Wh(512)]
// col' = 64*(n>>4) + g*16 + (n&15)
// ---------------------------------------------------------------------------
__global__ __launch_bounds__(256) void pack_w(const float* __restrict__ kfw,
                                              const float* __restrict__ kbw,
                                              f16* __restrict__ Wt) {
    unsigned idx = blockIdx.x * 256 + threadIdx.x;   // over 2*2048*1024
    int k    = idx & 1023;
    int colp = (idx >> 10) & 2047;
    int d    = idx >> 21;
    int cg = colp >> 6, g = (colp >> 4) & 3, ci = colp & 15;
    int n = cg * 16 + ci;
    const float* K = d ? kbw : kfw;
    Wt[idx] = (f16)K[(size_t)k * 2048 + g * 512 + n];
}

// ---------------------------------------------------------------------------
// Pack W1: W1t[col][k] fp16, k padded 3073 -> 3136
// ---------------------------------------------------------------------------
__global__ __launch_bounds__(256) void pack_w1(const float* __restrict__ W1,
                                               f16* __restrict__ W1t) {
    int idx = blockIdx.x * 256 + threadIdx.x;
    if (idx >= 512 * HC_K) return;
    int k = idx % HC_K, c = idx / HC_K;
    W1t[idx] = (k < 3073) ? (f16)W1[(size_t)k * MDIM + c] : (f16)0.0f;
}

// ---------------------------------------------------------------------------
// Deterministic rank-sort by seqlen DESC (tie: original index asc).
// ---------------------------------------------------------------------------
__global__ __launch_bounds__(256) void sort_rows(const int* __restrict__ sl1,
                                                 const int* __restrict__ sl2,
                                                 int* __restrict__ perm,
                                                 int* __restrict__ inv,
                                                 int* __restrict__ Acnt) {
    __shared__ int s_sh[ROWS];
    int tid = threadIdx.x;
    for (int i = tid; i < ROWS; i += 256) {
        int b = i & (BATCH - 1);
        s_sh[i] = (i < BATCH) ? sl1[b] : sl2[b];
    }
    __syncthreads();
    int i = blockIdx.x * 256 + tid;
    int key = (s_sh[i] << 12) - i;
    int rank = 0;
#pragma unroll 4
    for (int j = 0; j < ROWS; j += 4) {
        int4 v = *(const int4*)&s_sh[j];
        rank += ((v.x << 12) - (j + 0)) > key;
        rank += ((v.y << 12) - (j + 1)) > key;
        rank += ((v.z << 12) - (j + 2)) > key;
        rank += ((v.w << 12) - (j + 3)) > key;
    }
    perm[rank] = i;
    inv[i] = rank;
    if (blockIdx.x == 0 && tid < SEQL) {
        int c = 0;
#pragma unroll 4
        for (int j = 0; j < ROWS; j += 4) {
            int4 v = *(const int4*)&s_sh[j];
            c += (v.x > tid) + (v.y > tid) + (v.z > tid) + (v.w > tid);
        }
        Acnt[tid] = c;
    }
}

// ---------------------------------------------------------------------------
// MFMA on one staged k-tile: M=128, N=256, 8 waves (2 wr x 4 wc).
// ---------------------------------------------------------------------------
__device__ __forceinline__ void mma_tile(const f16* At, const f16* Bt,
                                         int l, int wr, int wc,
                                         f32x4 (&acc)[4][4]) {
#pragma unroll
    for (int kk = 0; kk < 2; ++kk) {
        f16x8 af[4], bv[4];
        const int slot = (l >> 4) + kk * 4;
#pragma unroll
        for (int fm = 0; fm < 4; ++fm) {
            int row = wr * 64 + fm * 16 + (l & 15);
            af[fm] = *(const f16x8*)&At[row * 64 + ((slot ^ (row & 7)) << 3)];
        }
#pragma unroll
        for (int fn = 0; fn < 4; ++fn) {
            int col = wc * 64 + fn * 16 + (l & 15);
            bv[fn] = *(const f16x8*)&Bt[col * 64 + ((slot ^ (col & 7)) << 3)];
        }
#pragma unroll
        for (int fm = 0; fm < 4; ++fm)
#pragma unroll
            for (int fn = 0; fn < 4; ++fn)
                acc[fm][fn] = __builtin_amdgcn_mfma_f32_16x16x32_f16(
                    af[fm], bv[fn], acc[fm][fn], 0, 0, 0);
    }
}

// ---------------------------------------------------------------------------
// x-part GEMM (K 0..511): embedding gather via glds16 (cached), dbuf.
// ---------------------------------------------------------------------------
__device__ __forceinline__ void gemm_x(const f16* __restrict__ embB,
                                       const int aoffX[2],
                                       const f16* __restrict__ Wt,
                                       const size_t boffX[4],
                                       const int dstA[2], const int dstB[4],
                                       int l, int wr, int wc,
                                       f16 (*At)[8192], f16 (*Bt)[16384],
                                       f32x4 (&acc)[4][4]) {
#pragma unroll
    for (int g = 0; g < 2; ++g) glds16(embB + aoffX[g], &At[0][dstA[g]]);
#pragma unroll
    for (int r = 0; r < 4; ++r) glds16(Wt + boffX[r], &Bt[0][dstB[r]]);
    __syncthreads();
#pragma unroll
    for (int kt = 0; kt < 8; ++kt) {
        const int cur = kt & 1;
        if (kt < 7) {
#pragma unroll
            for (int g = 0; g < 2; ++g)
                glds16(embB + aoffX[g] + (kt + 1) * 64, &At[cur ^ 1][dstA[g]]);
#pragma unroll
            for (int r = 0; r < 4; ++r)
                glds16(Wt + boffX[r] + (kt + 1) * 64, &Bt[cur ^ 1][dstB[r]]);
        }
        mma_tile(At[cur], Bt[cur], l, wr, wc, acc);
        __syncthreads();
    }
}

// ---------------------------------------------------------------------------
// h-part GEMM (K 512..1023): h staged via glds16c (sc0|sc1 -> coherent,
// coalesced, LDS-direct, compiler-tracked); B via glds16 dbuf.
// Structurally identical to gemm_x.
// ---------------------------------------------------------------------------
__device__ __forceinline__ void gemm_h(const f16* __restrict__ hin,
                                       const int aoffH[2],
                                       const f16* __restrict__ Wt,
                                       const size_t boffH[4],
                                       const int dstA[2], const int dstB[4],
                                       int l, int wr, int wc,
                                       f16 (*At)[8192], f16 (*Bt)[16384],
                                       f32x4 (&acc)[4][4]) {
#pragma unroll
    for (int g = 0; g < 2; ++g) glds16c(hin + aoffH[g], &At[0][dstA[g]]);
#pragma unroll
    for (int r = 0; r < 4; ++r) glds16(Wt + boffH[r], &Bt[0][dstB[r]]);
    __syncthreads();
#pragma unroll
    for (int kt = 0; kt < 8; ++kt) {
        const int cur = kt & 1;
        if (kt < 7) {
#pragma unroll
            for (int g = 0; g < 2; ++g)
                glds16c(hin + aoffH[g] + (kt + 1) * 64, &At[cur ^ 1][dstA[g]]);
#pragma unroll
            for (int r = 0; r < 4; ++r)
                glds16(Wt + boffH[r] + (kt + 1) * 64, &Bt[cur ^ 1][dstB[r]]);
        }
        mma_tile(At[cur], Bt[cur], l, wr, wc, acc);
        __syncthreads();
    }
}

// ---------------------------------------------------------------------------
// Persistent cooperative LSTM: all 64 steps, one dispatch.
// 256 blocks x 512 threads (1/CU). Block: (bx 0..7)x(by 0..15)x(dir 0..1).
// Per step: h-GEMM(t) -> epilogue (c in regs, packed u32 agent-atomic h
// stores) -> arrive -> x-GEMM(t+1) overlaps epoch wait -> wait.
// ---------------------------------------------------------------------------
__global__ __launch_bounds__(512, 2) void lstm_all(
    const int* __restrict__ in1, const int* __restrict__ in2,
    const int* __restrict__ sl1, const int* __restrict__ sl2,
    const int* __restrict__ perm, const int* __restrict__ Acnt,
    const f16* __restrict__ embH, const f16* __restrict__ Wt,
    const float* __restrict__ bfw, const float* __restrict__ bbw,
    f16* __restrict__ hb0, f16* __restrict__ hb1,
    int* __restrict__ scnt) {
    const int tid = threadIdx.x;
    const int l = tid & 63, w = tid >> 6;
    const int bid = blockIdx.x;
    const int grp  = bid & 7;                   // sync group (32 blocks each)
    const int slot = (bid >> 3) & 1;
    const int by   = bid >> 4;                  // row tile 0..15
    const int p    = grp * 2 + slot;            // 0..15
    const int bx   = p >> 1;                    // col tile 0..7 (256 cols)
    const int dir  = p & 1;

    __shared__ f16 At[2][8192];      // 32 KB
    __shared__ f16 Bt[2][16384];     // 64 KB
    __shared__ int toks[128];
    __shared__ int slens[128];
    __shared__ int acs[SEQL];

    int myb = 0, mys = 0;
    const int* myinp = in1;
    if (tid < 128) {
        int r = perm[by * 128 + tid];
        myb = r & (BATCH - 1);
        myinp = (r < BATCH) ? in1 : in2;
        mys = (r < BATCH) ? sl1[myb] : sl2[myb];
        slens[tid] = mys;
        int tt0 = dir ? (mys - 1) : 0;          // t=0 active for all (s>=1)
        toks[tid] = myinp[myb * SEQL + tt0];
    }
    if (tid < SEQL) acs[tid] = Acnt[tid];
    __syncthreads();

    // ---- constant staging descriptors
    const int kg8 = (((l & 7) ^ ((l >> 3) & 7))) * 8;
    int dstA[2]; size_t boffX[4], boffH[4]; int dstB[4]; int aoffH[2];
    const size_t habase = (size_t)(dir * ROWS + by * 128) << 9;
#pragma unroll
    for (int g = 0; g < 2; ++g) {
        dstA[g]  = (tid + g * 512) * 8;
        aoffH[g] = (int)(((tid >> 3) + g * 64) * 512 + kg8);
    }
#pragma unroll
    for (int r = 0; r < 4; ++r) {
        int col = (tid >> 3) + r * 64;          // 0..255
        boffX[r] = ((size_t)(dir * 2048 + bx * 256 + col) << 10) + kg8;
        boffH[r] = boffX[r] + 512;
        dstB[r]  = (tid + r * 512) * 8;
    }
    const int wr = w >> 2, wc = w & 3;

    const float* bias = dir ? bbw : bfw;
    const int ci = l & 15;
    const int cell = (bx * 4 + wc) * 16 + ci;   // 0..511
    float bg[4];
#pragma unroll
    for (int g = 0; g < 4; ++g) bg[g] = bias[g * 512 + cell];

    float creg[4][4];
    f32x4 acc[4][4];
#pragma unroll
    for (int i = 0; i < 4; ++i)
#pragma unroll
        for (int j = 0; j < 4; ++j) {
            creg[i][j] = 0.0f;
            acc[i][j] = (f32x4){0.f, 0.f, 0.f, 0.f};
        }

    // prologue: x-part of t=0 into acc
    {
        int ax[2];
#pragma unroll
        for (int g = 0; g < 2; ++g)
            ax[g] = toks[(tid >> 3) + g * 64] * 512 + kg8;
        gemm_x(embH, ax, Wt, boffX, dstA, dstB, l, wr, wc, At, Bt, acc);
    }

#pragma unroll 1
    for (int t = 0; t < SEQL; ++t) {
        const f16* hin = ((t & 1) ? hb1 : hb0) + habase;
        f16* hout      = ((t & 1) ? hb0 : hb1) + habase;
        if (by * 128 < acs[t]) {
            gemm_h(hin, aoffH, Wt, boffH, dstA, dstB, l, wr, wc, At, Bt, acc);
            // fused LSTM epilogue: lane owns 1 cell, 16 rows
#pragma unroll
            for (int fm = 0; fm < 4; ++fm) {
#pragma unroll
                for (int reg = 0; reg < 4; ++reg) {
                    int rl = wr * 64 + fm * 16 + (l >> 4) * 4 + reg;
                    float gi = acc[fm][0][reg] + bg[0];
                    float gj = acc[fm][1][reg] + bg[1];
                    float gf = acc[fm][2][reg] + bg[2];
                    float go = acc[fm][3][reg] + bg[3];
                    float cn = creg[fm][reg] * sigf(gf + 1.0f)
                             + sigf(gi) * tanh_fast(gj);
                    float hn = tanh_fast(cn) * sigf(go);
                    f16 hf = (f16)hn;
                    unsigned hv = *(unsigned short*)&hf;
                    unsigned ov = (unsigned)__shfl_xor((int)hv, 1);
                    if (t < slens[rl]) {
                        creg[fm][reg] = cn;
                        if ((l & 1) == 0) {
                            unsigned pk = hv | (ov << 16);
                            __hip_atomic_store(
                                (unsigned*)(hout + ((size_t)rl << 9) + cell),
                                pk, __ATOMIC_RELAXED, __HIP_MEMORY_SCOPE_AGENT);
                        }
                    }
                }
            }
        }
        if (t < SEQL - 1) {
            __syncthreads();   // drains vmcnt -> h stores complete
            if (tid == 0) {
                __builtin_amdgcn_fence(__ATOMIC_RELEASE, "agent");
                int old = __hip_atomic_fetch_add(&scnt[grp << 4], 1,
                    __ATOMIC_ACQ_REL, __HIP_MEMORY_SCOPE_AGENT);
                if (old == 32 * (t + 1) - 1) {
                    int m = __hip_atomic_fetch_add(&scnt[128], 1,
                        __ATOMIC_ACQ_REL, __HIP_MEMORY_SCOPE_AGENT);
                    if (m == 8 * (t + 1) - 1)
                        __hip_atomic_store(&scnt[144], t + 1,
                                           __ATOMIC_RELEASE,
                                           __HIP_MEMORY_SCOPE_AGENT);
                }
            }
            if (tid < 128) {
                int t1 = t + 1;
                int tt = dir ? ((t1 < mys) ? (mys - 1 - t1) : t1) : t1;
                toks[tid] = myinp[myb * SEQL + tt];
            }
#pragma unroll
            for (int i = 0; i < 4; ++i)
#pragma unroll
                for (int j = 0; j < 4; ++j)
                    acc[i][j] = (f32x4){0.f, 0.f, 0.f, 0.f};
            __syncthreads();
            if (by * 128 < acs[t + 1]) {
                int ax[2];
#pragma unroll
                for (int g = 0; g < 2; ++g)
                    ax[g] = toks[(tid >> 3) + g * 64] * 512 + kg8;
                gemm_x(embH, ax, Wt, boffX, dstA, dstB, l, wr, wc, At, Bt, acc);
            }
            if (tid == 0) {
                while (__hip_atomic_load(&scnt[144], __ATOMIC_ACQUIRE,
                                         __HIP_MEMORY_SCOPE_AGENT) < t + 1)
                    __builtin_amdgcn_s_sleep(2);
            }
            __syncthreads();
            __builtin_amdgcn_fence(__ATOMIC_ACQUIRE, "agent");
        }
    }
}

// ---------------------------------------------------------------------------
// Build h_combined fp16 [1024][3136]; final h of row r in buf[s&1], row inv[r].
// ---------------------------------------------------------------------------
__global__ __launch_bounds__(256) void build_hc(const f16* __restrict__ hbuf0,
                                                const f16* __restrict__ hbuf1,
                                                const int* __restrict__ sl1,
                                                const int* __restrict__ sl2,
                                                const int* __restrict__ inv,
                                                f16* __restrict__ hc) {
    int b = blockIdx.x;
    int tid = threadIdx.x;
    __shared__ float red[256];
    int s1 = sl1[b], s2 = sl2[b];
    int p1 = inv[b], p2 = inv[BATCH + b];
    const f16* hf1 = (s1 & 1) ? hbuf1 : hbuf0;
    const f16* hf2 = (s2 & 1) ? hbuf1 : hbuf0;
    float d = 0.0f;
    size_t base = (size_t)b * HC_K;
    for (int k = tid; k < 1024; k += 256) {
        int dir = k >> 9, kk = k & 511;
        float h1 = (float)hf1[((size_t)(dir * ROWS + p1) << 9) + kk];
        float h2 = (float)hf2[((size_t)(dir * ROWS + p2) << 9) + kk];
        hc[base + k]        = (f16)h1;
        hc[base + 1024 + k] = (f16)h2;
        hc[base + 2049 + k] = (f16)(h1 * h2);
        float df = h1 - h2;
        d += df * df;
    }
    red[tid] = d;
    __syncthreads();
    for (int s = 128; s > 0; s >>= 1) {
        if (tid < s) red[tid] += red[tid + s];
        __syncthreads();
    }
    if (tid == 0) hc[base + 2048] = (f16)red[0];
    if (tid < HC_K - 3073) hc[base + 3073 + tid] = (f16)0.0f;
}

// ---------------------------------------------------------------------------
// e1 = relu(hc @ W1 + b1)  fp16 MFMA 64x64 tile, BK=64, dbuf
// ---------------------------------------------------------------------------
__global__ __launch_bounds__(256) void mlp1(const f16* __restrict__ hc,
                                            const f16* __restrict__ W1t,
                                            const float* __restrict__ b1,
                                            float* __restrict__ e1) {
    const int bx = blockIdx.x, by = blockIdx.y, tid = threadIdx.x;
    const int l = tid & 63, w = tid >> 6;
    __shared__ f16 Atile[2][64 * 64];
    __shared__ f16 Btile[2][64 * 64];

    const int kg8 = (((l & 7) ^ ((l >> 3) & 7))) * 8;
    size_t aoff[2], boff[2]; int dst[2];
#pragma unroll
    for (int g = 0; g < 2; ++g) {
        int row = g * 32 + w * 8 + (l >> 3);
        aoff[g] = (size_t)(by * 64 + row) * HC_K + kg8;
        boff[g] = (size_t)(bx * 64 + row) * HC_K + kg8;
        dst[g]  = (g * 32 + w * 8) * 64;
    }

    f32x4 acc[2][2];
#pragma unroll
    for (int i = 0; i < 2; ++i)
#pragma unroll
        for (int j = 0; j < 2; ++j) acc[i][j] = (f32x4){0.f, 0.f, 0.f, 0.f};

    const int wr = w >> 1, wc = w & 1;

#pragma unroll
    for (int g = 0; g < 2; ++g) {
        glds16(hc + aoff[g], &Atile[0][dst[g]]);
        glds16(W1t + boff[g], &Btile[0][dst[g]]);
    }
    __syncthreads();

    int cur = 0;
    for (int kt = 0; kt < HC_K / 64; ++kt) {
        if (kt < HC_K / 64 - 1) {
            const int kn = (kt + 1) * 64;
#pragma unroll
            for (int g = 0; g < 2; ++g) {
                glds16(hc + aoff[g] + kn, &Atile[cur ^ 1][dst[g]]);
                glds16(W1t + boff[g] + kn, &Btile[cur ^ 1][dst[g]]);
            }
        }
#pragma unroll
        for (int kk = 0; kk < 2; ++kk) {
            f16x8 af[2], bv[2];
            const int slot = (l >> 4) + kk * 4;
#pragma unroll
            for (int fm = 0; fm < 2; ++fm) {
                int row = wr * 32 + fm * 16 + (l & 15);
                af[fm] = *(const f16x8*)&Atile[cur][row * 64 + (slot ^ (row & 7)) * 8];
            }
#pragma unroll
            for (int fn = 0; fn < 2; ++fn) {
                int col = wc * 32 + fn * 16 + (l & 15);
                bv[fn] = *(const f16x8*)&Btile[cur][col * 64 + (slot ^ (col & 7)) * 8];
            }
#pragma unroll
            for (int fm = 0; fm < 2; ++fm)
#pragma unroll
                for (int fn = 0; fn < 2; ++fn)
                    acc[fm][fn] = __builtin_amdgcn_mfma_f32_16x16x32_f16(
                        af[fm], bv[fn], acc[fm][fn], 0, 0, 0);
        }
        __syncthreads();
        cur ^= 1;
    }

#pragma unroll
    for (int fm = 0; fm < 2; ++fm) {
#pragma unroll
        for (int fn = 0; fn < 2; ++fn) {
#pragma unroll
            for (int reg = 0; reg < 4; ++reg) {
                int r = by * 64 + wr * 32 + fm * 16 + (l >> 4) * 4 + reg;
                int c = bx * 64 + wc * 32 + fn * 16 + (l & 15);
                float v = acc[fm][fn][reg] + b1[c];
                e1[(size_t)r * MDIM + c] = v > 0.0f ? v : 0.0f;
            }
        }
    }
}

// ---------------------------------------------------------------------------
// preds = e1 @ W2 + b2
// ---------------------------------------------------------------------------
__global__ __launch_bounds__(64) void mlp2(const float* __restrict__ e1,
                                           const float* __restrict__ W2,
                                           const float* __restrict__ b2,
                                           float* __restrict__ out) {
    int b = blockIdx.x, tid = threadIdx.x;
    float p0 = 0.f, p1 = 0.f;
    for (int k = tid; k < 512; k += 64) {
        float e = e1[(size_t)b * MDIM + k];
        p0 += e * W2[2 * k];
        p1 += e * W2[2 * k + 1];
    }
    for (int off = 32; off > 0; off >>= 1) {
        p0 += __shfl_down(p0, off);
        p1 += __shfl_down(p1, off);
    }
    if (tid == 0) {
        out[2 * b]     = p0 + b2[0];
        out[2 * b + 1] = p1 + b2[1];
    }
}

// ---------------------------------------------------------------------------
extern "C" void kernel_launch(void* const* d_in, const int* in_sizes, int n_in,
                              void* d_out, int out_size, void* d_ws, size_t ws_size,
                              hipStream_t stream) {
    (void)in_sizes; (void)n_in; (void)out_size; (void)ws_size;
    const int*   in1 = (const int*)d_in[0];
    const int*   in2 = (const int*)d_in[1];
    const int*   sl1 = (const int*)d_in[2];
    const int*   sl2 = (const int*)d_in[3];
    const float* emb = (const float*)d_in[4];
    const float* kfw = (const float*)d_in[5];
    const float* bfw = (const float*)d_in[6];
    const float* kbw = (const float*)d_in[7];
    const float* bbw = (const float*)d_in[8];
    const float* W1  = (const float*)d_in[9];
    const float* b1  = (const float*)d_in[10];
    const float* W2  = (const float*)d_in[11];
    const float* b2  = (const float*)d_in[12];
    float* out = (float*)d_out;

    char* base = (char*)d_ws;
    f16*   embH = (f16*)base;                      // 51,200,000 B
    f16*   Wt   = (f16*)(base + 51200000);         //  8,388,608 B
    f16*   W1t  = (f16*)(base + 59588608);         //  3,211,264 B
    f16*   h0   = (f16*)(base + 62799872);         //  4,194,304 B
    f16*   h1   = (f16*)(base + 66994176);         //  4,194,304 B
    f16*   hc   = (f16*)(base + 71188480);         //  6,422,528 B
    float* e1   = (float*)(base + 77611008);       //  2,097,152 B
    int*   perm = (int*)(base + 79708160);         //      8,192 B
    int*   inv  = (int*)(base + 79716352);         //      8,192 B
    int*   Acnt = (int*)(base + 79724544);         //        256 B
    int*   sync = (int*)(base + 79724800);         //      1,024 B

    hipMemsetAsync(h0, 0, 4194304, stream);        // h state at t=0
    hipMemsetAsync(sync, 0, 1024, stream);         // epoch counters

    sort_rows<<<ROWS / 256, 256, 0, stream>>>(sl1, sl2, perm, inv, Acnt);
    conv_emb<<<(VOCAB * D_EMB / 8 + 255) / 256, 256, 0, stream>>>(emb, embH, VOCAB * D_EMB / 8);
    pack_w<<<(2 * 2048 * 1024) / 256, 256, 0, stream>>>(kfw, kbw, Wt);
    pack_w1<<<(512 * HC_K + 255) / 256, 256, 0, stream>>>(W1, W1t);

    {
        const f16* embH_c = embH;
        const f16* Wt_c   = Wt;
        const int* perm_c = perm;
        const int* Acnt_c = Acnt;
        f16* h0_p = h0;
        f16* h1_p = h1;
        int* sync_p = sync;
        void* ka[] = {
            (void*)&in1, (void*)&in2, (void*)&sl1, (void*)&sl2,
            (void*)&perm_c, (void*)&Acnt_c, (void*)&embH_c, (void*)&Wt_c,
            (void*)&bfw, (void*)&bbw, (void*)&h0_p, (void*)&h1_p, (void*)&sync_p
        };
        hipLaunchCooperativeKernel((const void*)lstm_all, dim3(NBLK), dim3(512),
                                   ka, 0, stream);
    }

    build_hc<<<BATCH, 256, 0, stream>>>(h0, h1, sl1, sl2, inv, hc);
    mlp1<<<dim3(MDIM / 64, BATCH / 64), 256, 0, stream>>>(hc, W1t, b1, e1);
    mlp2<<<BATCH, 64, 0, stream>>>(e1, W2, b2, out);
}

// Round 11
// 3576.422 us; speedup vs baseline: 2.7514x; 1.9518x over previous
//
#include <hip/hip_runtime.h>
#include <hip/hip_bf16.h>
#include <cstddef>

// Problem constants
#define VOCAB 50000
#define D_EMB 512
#define HDIM  512
#define MDIM  512
#define BATCH 1024
#define SEQL  64
#define ROWS  2048          // 2 inputs * BATCH
#define HC_K  3136          // 3073 padded to 49*64
#define NBLK  256           // 8 bx * 2 dir * 16 by

typedef _Float16 f16;
typedef __attribute__((ext_vector_type(8))) _Float16 f16x8;
typedef __attribute__((ext_vector_type(4))) float f32x4;

__device__ __forceinline__ float sigf(float x) {
    return 1.0f / (1.0f + __expf(-x));
}
__device__ __forceinline__ float tanh_fast(float x) {
    x = fminf(30.0f, fmaxf(-30.0f, x));
    float t = __expf(-2.0f * x);
    return (1.0f - t) / (1.0f + t);
}
// cached global->LDS (16B/lane)
__device__ __forceinline__ void glds16(const void* g, const void* lds) {
    __builtin_amdgcn_global_load_lds(
        (const __attribute__((address_space(1))) unsigned int*)g,
        (__attribute__((address_space(3))) unsigned int*)lds, 16, 0, 0);
}

// ---------------------------------------------------------------------------
// fp32 -> fp16 embedding convert
// ---------------------------------------------------------------------------
__global__ __launch_bounds__(256) void conv_emb(const float* __restrict__ src,
                                                f16* __restrict__ dst, int n8) {
    int i = blockIdx.x * 256 + threadIdx.x;
    if (i >= n8) return;
    const float4* s = (const float4*)src + (size_t)i * 2;
    float4 a = s[0], b = s[1];
    f16x8 o = {(f16)a.x, (f16)a.y, (f16)a.z, (f16)a.w,
               (f16)b.x, (f16)b.y, (f16)b.z, (f16)b.w};
    *(f16x8*)&dst[(size_t)i * 8] = o;
}

// ---------------------------------------------------------------------------
// Pack LSTM weights: Wt[dir][col'][k] (fp16), k = [Wx(512);Wh(512)]
// col' = 64*(n>>4) + g*16 + (n&15)
// ---------------------------------------------------------------------------
__global__ __launch_bounds__(256) void pack_w(const float* __restrict__ kfw,
                                              const float* __restrict__ kbw,
                                              f16* __restrict__ Wt) {
    unsigned idx = blockIdx.x * 256 + threadIdx.x;   // over 2*2048*1024
    int k    = idx & 1023;
    int colp = (idx >> 10) & 2047;
    int d    = idx >> 21;
    int cg = colp >> 6, g = (colp >> 4) & 3, ci = colp & 15;
    int n = cg * 16 + ci;
    const float* K = d ? kbw : kfw;
    Wt[idx] = (f16)K[(size_t)k * 2048 + g * 512 + n];
}

// ---------------------------------------------------------------------------
// Pack W1: W1t[col][k] fp16, k padded 3073 -> 3136
// ---------------------------------------------------------------------------
__global__ __launch_bounds__(256) void pack_w1(const float* __restrict__ W1,
                                               f16* __restrict__ W1t) {
    int idx = blockIdx.x * 256 + threadIdx.x;
    if (idx >= 512 * HC_K) return;
    int k = idx % HC_K, c = idx / HC_K;
    W1t[idx] = (k < 3073) ? (f16)W1[(size_t)k * MDIM + c] : (f16)0.0f;
}

// ---------------------------------------------------------------------------
// Deterministic rank-sort by seqlen DESC (tie: original index asc).
// ---------------------------------------------------------------------------
__global__ __launch_bounds__(256) void sort_rows(const int* __restrict__ sl1,
                                                 const int* __restrict__ sl2,
                                                 int* __restrict__ perm,
                                                 int* __restrict__ inv,
                                                 int* __restrict__ Acnt) {
    __shared__ int s_sh[ROWS];
    int tid = threadIdx.x;
    for (int i = tid; i < ROWS; i += 256) {
        int b = i & (BATCH - 1);
        s_sh[i] = (i < BATCH) ? sl1[b] : sl2[b];
    }
    __syncthreads();
    int i = blockIdx.x * 256 + tid;
    int key = (s_sh[i] << 12) - i;
    int rank = 0;
#pragma unroll 4
    for (int j = 0; j < ROWS; j += 4) {
        int4 v = *(const int4*)&s_sh[j];
        rank += ((v.x << 12) - (j + 0)) > key;
        rank += ((v.y << 12) - (j + 1)) > key;
        rank += ((v.z << 12) - (j + 2)) > key;
        rank += ((v.w << 12) - (j + 3)) > key;
    }
    perm[rank] = i;
    inv[i] = rank;
    if (blockIdx.x == 0 && tid < SEQL) {
        int c = 0;
#pragma unroll 4
        for (int j = 0; j < ROWS; j += 4) {
            int4 v = *(const int4*)&s_sh[j];
            c += (v.x > tid) + (v.y > tid) + (v.z > tid) + (v.w > tid);
        }
        Acnt[tid] = c;
    }
}

// ---------------------------------------------------------------------------
// MFMA on one staged k-tile: M=128, N=256, 8 waves (2 wr x 4 wc).
// ---------------------------------------------------------------------------
__device__ __forceinline__ void mma_tile(const f16* At, const f16* Bt,
                                         int l, int wr, int wc,
                                         f32x4 (&acc)[4][4]) {
#pragma unroll
    for (int kk = 0; kk < 2; ++kk) {
        f16x8 af[4], bv[4];
        const int slot = (l >> 4) + kk * 4;
#pragma unroll
        for (int fm = 0; fm < 4; ++fm) {
            int row = wr * 64 + fm * 16 + (l & 15);
            af[fm] = *(const f16x8*)&At[row * 64 + ((slot ^ (row & 7)) << 3)];
        }
#pragma unroll
        for (int fn = 0; fn < 4; ++fn) {
            int col = wc * 64 + fn * 16 + (l & 15);
            bv[fn] = *(const f16x8*)&Bt[col * 64 + ((slot ^ (col & 7)) << 3)];
        }
#pragma unroll
        for (int fm = 0; fm < 4; ++fm)
#pragma unroll
            for (int fn = 0; fn < 4; ++fn)
                acc[fm][fn] = __builtin_amdgcn_mfma_f32_16x16x32_f16(
                    af[fm], bv[fn], acc[fm][fn], 0, 0, 0);
    }
}

// ---------------------------------------------------------------------------
// Half-K GEMM (512): A (emb rows or h rows) + B (weights) via cached glds16,
// classic double-buffer. Used for both x-part and h-part (h coherence comes
// from the per-step L2 invalidate done by the epoch acquire fence).
// ---------------------------------------------------------------------------
__device__ __forceinline__ void gemm512(const f16* __restrict__ Abase,
                                        const int aoff[2],
                                        const f16* __restrict__ Wt,
                                        const size_t boff[4],
                                        const int dstA[2], const int dstB[4],
                                        int l, int wr, int wc,
                                        f16 (*At)[8192], f16 (*Bt)[16384],
                                        f32x4 (&acc)[4][4]) {
#pragma unroll
    for (int g = 0; g < 2; ++g) glds16(Abase + aoff[g], &At[0][dstA[g]]);
#pragma unroll
    for (int r = 0; r < 4; ++r) glds16(Wt + boff[r], &Bt[0][dstB[r]]);
    __syncthreads();
#pragma unroll
    for (int kt = 0; kt < 8; ++kt) {
        const int cur = kt & 1;
        if (kt < 7) {
#pragma unroll
            for (int g = 0; g < 2; ++g)
                glds16(Abase + aoff[g] + (kt + 1) * 64, &At[cur ^ 1][dstA[g]]);
#pragma unroll
            for (int r = 0; r < 4; ++r)
                glds16(Wt + boff[r] + (kt + 1) * 64, &Bt[cur ^ 1][dstB[r]]);
        }
        mma_tile(At[cur], Bt[cur], l, wr, wc, acc);
        __syncthreads();
    }
}

// ---------------------------------------------------------------------------
// Persistent cooperative LSTM: all 64 steps, one dispatch.
// 256 blocks x 512 threads (1/CU). XCD-aware mapping (bid%8 = XCD):
//   x=bid&7, j=bid>>3:  dir=x>>2, by=(x&3)+(j&3)*4, bx=j>>2
// -> all 8 bx-blocks sharing an h row-tile AND one dir's 4MB weight set sit
//    on one XCD (L2-resident after first fetch each step).
// Per step: h-GEMM(t) -> epilogue (c in regs, packed u32 agent-atomic h
// stores) -> arrive -> x-GEMM(t+1) overlaps epoch wait (RELAXED poll)
// -> acquire fence (L2 invalidate) -> next step reads fresh h, cached.
// ---------------------------------------------------------------------------
__global__ __launch_bounds__(512, 2) void lstm_all(
    const int* __restrict__ in1, const int* __restrict__ in2,
    const int* __restrict__ sl1, const int* __restrict__ sl2,
    const int* __restrict__ perm, const int* __restrict__ Acnt,
    const f16* __restrict__ embH, const f16* __restrict__ Wt,
    const float* __restrict__ bfw, const float* __restrict__ bbw,
    f16* __restrict__ hb0, f16* __restrict__ hb1,
    int* __restrict__ scnt) {
    const int tid = threadIdx.x;
    const int l = tid & 63, w = tid >> 6;
    const int bid = blockIdx.x;
    const int x   = bid & 7;                // XCD (bid%8 round-robin)
    const int j   = bid >> 3;               // 0..31 within XCD
    const int dir = x >> 2;
    const int by  = (x & 3) + (j & 3) * 4;  // row tile 0..15
    const int bx  = j >> 2;                 // col tile 0..7 (256 cols)
    const int grp = x;                      // sync group = XCD, 32 blocks

    __shared__ f16 At[2][8192];      // 32 KB
    __shared__ f16 Bt[2][16384];     // 64 KB
    __shared__ int toks[128];
    __shared__ int slens[128];
    __shared__ int acs[SEQL];

    int myb = 0, mys = 0;
    const int* myinp = in1;
    if (tid < 128) {
        int r = perm[by * 128 + tid];
        myb = r & (BATCH - 1);
        myinp = (r < BATCH) ? in1 : in2;
        mys = (r < BATCH) ? sl1[myb] : sl2[myb];
        slens[tid] = mys;
        int tt0 = dir ? (mys - 1) : 0;      // t=0 active for all (s>=1)
        toks[tid] = myinp[myb * SEQL + tt0];
    }
    if (tid < SEQL) acs[tid] = Acnt[tid];
    __syncthreads();

    // ---- constant staging descriptors
    const int kg8 = (((l & 7) ^ ((l >> 3) & 7))) * 8;
    int dstA[2]; size_t boffX[4], boffH[4]; int dstB[4]; int aoffH[2];
    const size_t habase = (size_t)(dir * ROWS + by * 128) << 9;
#pragma unroll
    for (int g = 0; g < 2; ++g) {
        dstA[g]  = (tid + g * 512) * 8;
        aoffH[g] = (int)(((tid >> 3) + g * 64) * 512 + kg8);
    }
#pragma unroll
    for (int r = 0; r < 4; ++r) {
        int col = (tid >> 3) + r * 64;      // 0..255
        boffX[r] = ((size_t)(dir * 2048 + bx * 256 + col) << 10) + kg8;
        boffH[r] = boffX[r] + 512;
        dstB[r]  = (tid + r * 512) * 8;
    }
    const int wr = w >> 2, wc = w & 3;

    const float* bias = dir ? bbw : bfw;
    const int ci = l & 15;
    const int cell = (bx * 4 + wc) * 16 + ci;   // 0..511
    float bg[4];
#pragma unroll
    for (int g = 0; g < 4; ++g) bg[g] = bias[g * 512 + cell];

    float creg[4][4];
    f32x4 acc[4][4];
#pragma unroll
    for (int i = 0; i < 4; ++i)
#pragma unroll
        for (int j2 = 0; j2 < 4; ++j2) {
            creg[i][j2] = 0.0f;
            acc[i][j2] = (f32x4){0.f, 0.f, 0.f, 0.f};
        }

    // prologue: x-part of t=0 into acc
    {
        int ax[2];
#pragma unroll
        for (int g = 0; g < 2; ++g)
            ax[g] = toks[(tid >> 3) + g * 64] * 512 + kg8;
        gemm512(embH, ax, Wt, boffX, dstA, dstB, l, wr, wc, At, Bt, acc);
    }

#pragma unroll 1
    for (int t = 0; t < SEQL; ++t) {
        const f16* hin = ((t & 1) ? hb1 : hb0) + habase;
        f16* hout      = ((t & 1) ? hb0 : hb1) + habase;
        if (by * 128 < acs[t]) {
            gemm512(hin, aoffH, Wt, boffH, dstA, dstB, l, wr, wc, At, Bt, acc);
            // fused LSTM epilogue: lane owns 1 cell, 16 rows
#pragma unroll
            for (int fm = 0; fm < 4; ++fm) {
#pragma unroll
                for (int reg = 0; reg < 4; ++reg) {
                    int rl = wr * 64 + fm * 16 + (l >> 4) * 4 + reg;
                    float gi = acc[fm][0][reg] + bg[0];
                    float gj = acc[fm][1][reg] + bg[1];
                    float gf = acc[fm][2][reg] + bg[2];
                    float go = acc[fm][3][reg] + bg[3];
                    float cn = creg[fm][reg] * sigf(gf + 1.0f)
                             + sigf(gi) * tanh_fast(gj);
                    float hn = tanh_fast(cn) * sigf(go);
                    f16 hf = (f16)hn;
                    unsigned hv = *(unsigned short*)&hf;
                    unsigned ov = (unsigned)__shfl_xor((int)hv, 1);
                    if (t < slens[rl]) {
                        creg[fm][reg] = cn;
                        if ((l & 1) == 0) {
                            unsigned pk = hv | (ov << 16);
                            __hip_atomic_store(
                                (unsigned*)(hout + ((size_t)rl << 9) + cell),
                                pk, __ATOMIC_RELAXED, __HIP_MEMORY_SCOPE_AGENT);
                        }
                    }
                }
            }
        }
        if (t < SEQL - 1) {
            __syncthreads();   // drains vmcnt -> h stores complete
            if (tid == 0) {
                __builtin_amdgcn_fence(__ATOMIC_RELEASE, "agent");
                int old = __hip_atomic_fetch_add(&scnt[grp << 4], 1,
                    __ATOMIC_ACQ_REL, __HIP_MEMORY_SCOPE_AGENT);
                if (old == 32 * (t + 1) - 1) {
                    int m = __hip_atomic_fetch_add(&scnt[128], 1,
                        __ATOMIC_ACQ_REL, __HIP_MEMORY_SCOPE_AGENT);
                    if (m == 8 * (t + 1) - 1)
                        __hip_atomic_store(&scnt[144], t + 1,
                                           __ATOMIC_RELEASE,
                                           __HIP_MEMORY_SCOPE_AGENT);
                }
            }
            if (tid < 128) {
                int t1 = t + 1;
                int tt = dir ? ((t1 < mys) ? (mys - 1 - t1) : t1) : t1;
                toks[tid] = myinp[myb * SEQL + tt];
            }
#pragma unroll
            for (int i = 0; i < 4; ++i)
#pragma unroll
                for (int j2 = 0; j2 < 4; ++j2)
                    acc[i][j2] = (f32x4){0.f, 0.f, 0.f, 0.f};
            __syncthreads();
            if (by * 128 < acs[t + 1]) {
                int ax[2];
#pragma unroll
                for (int g = 0; g < 2; ++g)
                    ax[g] = toks[(tid >> 3) + g * 64] * 512 + kg8;
                gemm512(embH, ax, Wt, boffX, dstA, dstB, l, wr, wc, At, Bt, acc);
            }
            if (tid == 0) {
                while (__hip_atomic_load(&scnt[144], __ATOMIC_RELAXED,
                                         __HIP_MEMORY_SCOPE_AGENT) < t + 1)
                    __builtin_amdgcn_s_sleep(2);
            }
            __syncthreads();
            // acquire: invalidate L1/L2 so next step's cached h loads are fresh
            __builtin_amdgcn_fence(__ATOMIC_ACQUIRE, "agent");
        }
    }
}

// ---------------------------------------------------------------------------
// Build h_combined fp16 [1024][3136]; final h of row r in buf[s&1], row inv[r].
// ---------------------------------------------------------------------------
__global__ __launch_bounds__(256) void build_hc(const f16* __restrict__ hbuf0,
                                                const f16* __restrict__ hbuf1,
                                                const int* __restrict__ sl1,
                                                const int* __restrict__ sl2,
                                                const int* __restrict__ inv,
                                                f16* __restrict__ hc) {
    int b = blockIdx.x;
    int tid = threadIdx.x;
    __shared__ float red[256];
    int s1 = sl1[b], s2 = sl2[b];
    int p1 = inv[b], p2 = inv[BATCH + b];
    const f16* hf1 = (s1 & 1) ? hbuf1 : hbuf0;
    const f16* hf2 = (s2 & 1) ? hbuf1 : hbuf0;
    float d = 0.0f;
    size_t base = (size_t)b * HC_K;
    for (int k = tid; k < 1024; k += 256) {
        int dir = k >> 9, kk = k & 511;
        float h1 = (float)hf1[((size_t)(dir * ROWS + p1) << 9) + kk];
        float h2 = (float)hf2[((size_t)(dir * ROWS + p2) << 9) + kk];
        hc[base + k]        = (f16)h1;
        hc[base + 1024 + k] = (f16)h2;
        hc[base + 2049 + k] = (f16)(h1 * h2);
        float df = h1 - h2;
        d += df * df;
    }
    red[tid] = d;
    __syncthreads();
    for (int s = 128; s > 0; s >>= 1) {
        if (tid < s) red[tid] += red[tid + s];
        __syncthreads();
    }
    if (tid == 0) hc[base + 2048] = (f16)red[0];
    if (tid < HC_K - 3073) hc[base + 3073 + tid] = (f16)0.0f;
}

// ---------------------------------------------------------------------------
// e1 = relu(hc @ W1 + b1)  fp16 MFMA 64x64 tile, BK=64, dbuf
// ---------------------------------------------------------------------------
__global__ __launch_bounds__(256) void mlp1(const f16* __restrict__ hc,
                                            const f16* __restrict__ W1t,
                                            const float* __restrict__ b1,
                                            float* __restrict__ e1) {
    const int bx = blockIdx.x, by = blockIdx.y, tid = threadIdx.x;
    const int l = tid & 63, w = tid >> 6;
    __shared__ f16 Atile[2][64 * 64];
    __shared__ f16 Btile[2][64 * 64];

    const int kg8 = (((l & 7) ^ ((l >> 3) & 7))) * 8;
    size_t aoff[2], boff[2]; int dst[2];
#pragma unroll
    for (int g = 0; g < 2; ++g) {
        int row = g * 32 + w * 8 + (l >> 3);
        aoff[g] = (size_t)(by * 64 + row) * HC_K + kg8;
        boff[g] = (size_t)(bx * 64 + row) * HC_K + kg8;
        dst[g]  = (g * 32 + w * 8) * 64;
    }

    f32x4 acc[2][2];
#pragma unroll
    for (int i = 0; i < 2; ++i)
#pragma unroll
        for (int j = 0; j < 2; ++j) acc[i][j] = (f32x4){0.f, 0.f, 0.f, 0.f};

    const int wr = w >> 1, wc = w & 1;

#pragma unroll
    for (int g = 0; g < 2; ++g) {
        glds16(hc + aoff[g], &Atile[0][dst[g]]);
        glds16(W1t + boff[g], &Btile[0][dst[g]]);
    }
    __syncthreads();

    int cur = 0;
    for (int kt = 0; kt < HC_K / 64; ++kt) {
        if (kt < HC_K / 64 - 1) {
            const int kn = (kt + 1) * 64;
#pragma unroll
            for (int g = 0; g < 2; ++g) {
                glds16(hc + aoff[g] + kn, &Atile[cur ^ 1][dst[g]]);
                glds16(W1t + boff[g] + kn, &Btile[cur ^ 1][dst[g]]);
            }
        }
#pragma unroll
        for (int kk = 0; kk < 2; ++kk) {
            f16x8 af[2], bv[2];
            const int slot = (l >> 4) + kk * 4;
#pragma unroll
            for (int fm = 0; fm < 2; ++fm) {
                int row = wr * 32 + fm * 16 + (l & 15);
                af[fm] = *(const f16x8*)&Atile[cur][row * 64 + (slot ^ (row & 7)) * 8];
            }
#pragma unroll
            for (int fn = 0; fn < 2; ++fn) {
                int col = wc * 32 + fn * 16 + (l & 15);
                bv[fn] = *(const f16x8*)&Btile[cur][col * 64 + (slot ^ (col & 7)) * 8];
            }
#pragma unroll
            for (int fm = 0; fm < 2; ++fm)
#pragma unroll
                for (int fn = 0; fn < 2; ++fn)
                    acc[fm][fn] = __builtin_amdgcn_mfma_f32_16x16x32_f16(
                        af[fm], bv[fn], acc[fm][fn], 0, 0, 0);
        }
        __syncthreads();
        cur ^= 1;
    }

#pragma unroll
    for (int fm = 0; fm < 2; ++fm) {
#pragma unroll
        for (int fn = 0; fn < 2; ++fn) {
#pragma unroll
            for (int reg = 0; reg < 4; ++reg) {
                int r = by * 64 + wr * 32 + fm * 16 + (l >> 4) * 4 + reg;
                int c = bx * 64 + wc * 32 + fn * 16 + (l & 15);
                float v = acc[fm][fn][reg] + b1[c];
                e1[(size_t)r * MDIM + c] = v > 0.0f ? v : 0.0f;
            }
        }
    }
}

// ---------------------------------------------------------------------------
// preds = e1 @ W2 + b2
// ---------------------------------------------------------------------------
__global__ __launch_bounds__(64) void mlp2(const float* __restrict__ e1,
                                           const float* __restrict__ W2,
                                           const float* __restrict__ b2,
                                           float* __restrict__ out) {
    int b = blockIdx.x, tid = threadIdx.x;
    float p0 = 0.f, p1 = 0.f;
    for (int k = tid; k < 512; k += 64) {
        float e = e1[(size_t)b * MDIM + k];
        p0 += e * W2[2 * k];
        p1 += e * W2[2 * k + 1];
    }
    for (int off = 32; off > 0; off >>= 1) {
        p0 += __shfl_down(p0, off);
        p1 += __shfl_down(p1, off);
    }
    if (tid == 0) {
        out[2 * b]     = p0 + b2[0];
        out[2 * b + 1] = p1 + b2[1];
    }
}

// ---------------------------------------------------------------------------
extern "C" void kernel_launch(void* const* d_in, const int* in_sizes, int n_in,
                              void* d_out, int out_size, void* d_ws, size_t ws_size,
                              hipStream_t stream) {
    (void)in_sizes; (void)n_in; (void)out_size; (void)ws_size;
    const int*   in1 = (const int*)d_in[0];
    const int*   in2 = (const int*)d_in[1];
    const int*   sl1 = (const int*)d_in[2];
    const int*   sl2 = (const int*)d_in[3];
    const float* emb = (const float*)d_in[4];
    const float* kfw = (const float*)d_in[5];
    const float* bfw = (const float*)d_in[6];
    const float* kbw = (const float*)d_in[7];
    const float* bbw = (const float*)d_in[8];
    const float* W1  = (const float*)d_in[9];
    const float* b1  = (const float*)d_in[10];
    const float* W2  = (const float*)d_in[11];
    const float* b2  = (const float*)d_in[12];
    float* out = (float*)d_out;

    char* base = (char*)d_ws;
    f16*   embH = (f16*)base;                      // 51,200,000 B
    f16*   Wt   = (f16*)(base + 51200000);         //  8,388,608 B
    f16*   W1t  = (f16*)(base + 59588608);         //  3,211,264 B
    f16*   h0   = (f16*)(base + 62799872);         //  4,194,304 B
    f16*   h1   = (f16*)(base + 66994176);         //  4,194,304 B
    f16*   hc   = (f16*)(base + 71188480);         //  6,422,528 B
    float* e1   = (float*)(base + 77611008);       //  2,097,152 B
    int*   perm = (int*)(base + 79708160);         //      8,192 B
    int*   inv  = (int*)(base + 79716352);         //      8,192 B
    int*   Acnt = (int*)(base + 79724544);         //        256 B
    int*   sync = (int*)(base + 79724800);         //      1,024 B

    hipMemsetAsync(h0, 0, 4194304, stream);        // h state at t=0
    hipMemsetAsync(sync, 0, 1024, stream);         // epoch counters

    sort_rows<<<ROWS / 256, 256, 0, stream>>>(sl1, sl2, perm, inv, Acnt);
    conv_emb<<<(VOCAB * D_EMB / 8 + 255) / 256, 256, 0, stream>>>(emb, embH, VOCAB * D_EMB / 8);
    pack_w<<<(2 * 2048 * 1024) / 256, 256, 0, stream>>>(kfw, kbw, Wt);
    pack_w1<<<(512 * HC_K + 255) / 256, 256, 0, stream>>>(W1, W1t);

    {
        const f16* embH_c = embH;
        const f16* Wt_c   = Wt;
        const int* perm_c = perm;
        const int* Acnt_c = Acnt;
        f16* h0_p = h0;
        f16* h1_p = h1;
        int* sync_p = sync;
        void* ka[] = {
            (void*)&in1, (void*)&in2, (void*)&sl1, (void*)&sl2,
            (void*)&perm_c, (void*)&Acnt_c, (void*)&embH_c, (void*)&Wt_c,
            (void*)&bfw, (void*)&bbw, (void*)&h0_p, (void*)&h1_p, (void*)&sync_p
        };
        hipLaunchCooperativeKernel((const void*)lstm_all, dim3(NBLK), dim3(512),
                                   ka, 0, stream);
    }

    build_hc<<<BATCH, 256, 0, stream>>>(h0, h1, sl1, sl2, inv, hc);
    mlp1<<<dim3(MDIM / 64, BATCH / 64), 256, 0, stream>>>(hc, W1t, b1, e1);
    mlp2<<<BATCH, 64, 0, stream>>>(e1, W2, b2, out);
}

// Round 12
// 2264.117 us; speedup vs baseline: 4.3461x; 1.5796x over previous
//
#include <hip/hip_runtime.h>
#include <hip/hip_bf16.h>
#include <cstddef>

// Problem constants
#define VOCAB 50000
#define D_EMB 512
#define HDIM  512
#define MDIM  512
#define BATCH 1024
#define SEQL  64
#define ROWS  2048          // 2 inputs * BATCH
#define HC_K  3136          // 3073 padded to 49*64
#define NBLK  256           // 8 bx * 2 dir * 16 by  (roles negotiated per-XCD)

typedef _Float16 f16;
typedef __attribute__((ext_vector_type(8))) _Float16 f16x8;
typedef __attribute__((ext_vector_type(4))) float f32x4;

__device__ __forceinline__ float sigf(float x) {
    return 1.0f / (1.0f + __expf(-x));
}
__device__ __forceinline__ float tanh_fast(float x) {
    x = fminf(30.0f, fmaxf(-30.0f, x));
    float t = __expf(-2.0f * x);
    return (1.0f - t) / (1.0f + t);
}
// global->LDS (16B/lane), AUX: 0=cached, 2=NT (L2 no-pollute stream)
template <int AUX>
__device__ __forceinline__ void glds16(const void* g, const void* lds) {
    __builtin_amdgcn_global_load_lds(
        (const __attribute__((address_space(1))) unsigned int*)g,
        (__attribute__((address_space(3))) unsigned int*)lds, 16, 0, AUX);
}

// ---------------------------------------------------------------------------
// fp32 -> fp16 embedding convert
// ---------------------------------------------------------------------------
__global__ __launch_bounds__(256) void conv_emb(const float* __restrict__ src,
                                                f16* __restrict__ dst, int n8) {
    int i = blockIdx.x * 256 + threadIdx.x;
    if (i >= n8) return;
    const float4* s = (const float4*)src + (size_t)i * 2;
    float4 a = s[0], b = s[1];
    f16x8 o = {(f16)a.x, (f16)a.y, (f16)a.z, (f16)a.w,
               (f16)b.x, (f16)b.y, (f16)b.z, (f16)b.w};
    *(f16x8*)&dst[(size_t)i * 8] = o;
}

// ---------------------------------------------------------------------------
// Pack LSTM weights: Wt[dir][col'][k] (fp16), k = [Wx(512);Wh(512)]
// col' = 64*(n>>4) + g*16 + (n&15)
// ---------------------------------------------------------------------------
__global__ __launch_bounds__(256) void pack_w(const float* __restrict__ kfw,
                                              const float* __restrict__ kbw,
                                              f16* __restrict__ Wt) {
    unsigned idx = blockIdx.x * 256 + threadIdx.x;   // over 2*2048*1024
    int k    = idx & 1023;
    int colp = (idx >> 10) & 2047;
    int d    = idx >> 21;
    int cg = colp >> 6, g = (colp >> 4) & 3, ci = colp & 15;
    int n = cg * 16 + ci;
    const float* K = d ? kbw : kfw;
    Wt[idx] = (f16)K[(size_t)k * 2048 + g * 512 + n];
}

// ---------------------------------------------------------------------------
// Pack W1: W1t[col][k] fp16, k padded 3073 -> 3136
// ---------------------------------------------------------------------------
__global__ __launch_bounds__(256) void pack_w1(const float* __restrict__ W1,
                                               f16* __restrict__ W1t) {
    int idx = blockIdx.x * 256 + threadIdx.x;
    if (idx >= 512 * HC_K) return;
    int k = idx % HC_K, c = idx / HC_K;
    W1t[idx] = (k < 3073) ? (f16)W1[(size_t)k * MDIM + c] : (f16)0.0f;
}

// ---------------------------------------------------------------------------
// Deterministic rank-sort by seqlen DESC (tie: original index asc).
// ---------------------------------------------------------------------------
__global__ __launch_bounds__(256) void sort_rows(const int* __restrict__ sl1,
                                                 const int* __restrict__ sl2,
                                                 int* __restrict__ perm,
                                                 int* __restrict__ inv,
                                                 int* __restrict__ Acnt) {
    __shared__ int s_sh[ROWS];
    int tid = threadIdx.x;
    for (int i = tid; i < ROWS; i += 256) {
        int b = i & (BATCH - 1);
        s_sh[i] = (i < BATCH) ? sl1[b] : sl2[b];
    }
    __syncthreads();
    int i = blockIdx.x * 256 + tid;
    int key = (s_sh[i] << 12) - i;
    int rank = 0;
#pragma unroll 4
    for (int j = 0; j < ROWS; j += 4) {
        int4 v = *(const int4*)&s_sh[j];
        rank += ((v.x << 12) - (j + 0)) > key;
        rank += ((v.y << 12) - (j + 1)) > key;
        rank += ((v.z << 12) - (j + 2)) > key;
        rank += ((v.w << 12) - (j + 3)) > key;
    }
    perm[rank] = i;
    inv[i] = rank;
    if (blockIdx.x == 0 && tid < SEQL) {
        int c = 0;
#pragma unroll 4
        for (int j = 0; j < ROWS; j += 4) {
            int4 v = *(const int4*)&s_sh[j];
            c += (v.x > tid) + (v.y > tid) + (v.z > tid) + (v.w > tid);
        }
        Acnt[tid] = c;
    }
}

// ---------------------------------------------------------------------------
// MFMA on one staged k-tile: M=128, N=256, 8 waves (2 wr x 4 wc).
// ---------------------------------------------------------------------------
__device__ __forceinline__ void mma_tile(const f16* At, const f16* Bt,
                                         int l, int wr, int wc,
                                         f32x4 (&acc)[4][4]) {
#pragma unroll
    for (int kk = 0; kk < 2; ++kk) {
        f16x8 af[4], bv[4];
        const int slot = (l >> 4) + kk * 4;
#pragma unroll
        for (int fm = 0; fm < 4; ++fm) {
            int row = wr * 64 + fm * 16 + (l & 15);
            af[fm] = *(const f16x8*)&At[row * 64 + ((slot ^ (row & 7)) << 3)];
        }
#pragma unroll
        for (int fn = 0; fn < 4; ++fn) {
            int col = wc * 64 + fn * 16 + (l & 15);
            bv[fn] = *(const f16x8*)&Bt[col * 64 + ((slot ^ (col & 7)) << 3)];
        }
#pragma unroll
        for (int fm = 0; fm < 4; ++fm)
#pragma unroll
            for (int fn = 0; fn < 4; ++fn)
                acc[fm][fn] = __builtin_amdgcn_mfma_f32_16x16x32_f16(
                    af[fm], bv[fn], acc[fm][fn], 0, 0, 0);
    }
}

// ---------------------------------------------------------------------------
// Half-K GEMM (512): A via glds16<AUXA> (emb: NT stream; h: cached L2-local),
// B (weights) cached. Classic double-buffer.
// ---------------------------------------------------------------------------
template <int AUXA>
__device__ __forceinline__ void gemm512(const f16* __restrict__ Abase,
                                        const int aoff[2],
                                        const f16* __restrict__ Wt,
                                        const size_t boff[4],
                                        const int dstA[2], const int dstB[4],
                                        int l, int wr, int wc,
                                        f16 (*At)[8192], f16 (*Bt)[16384],
                                        f32x4 (&acc)[4][4]) {
#pragma unroll
    for (int g = 0; g < 2; ++g) glds16<AUXA>(Abase + aoff[g], &At[0][dstA[g]]);
#pragma unroll
    for (int r = 0; r < 4; ++r) glds16<0>(Wt + boff[r], &Bt[0][dstB[r]]);
    __syncthreads();
#pragma unroll
    for (int kt = 0; kt < 8; ++kt) {
        const int cur = kt & 1;
        if (kt < 7) {
#pragma unroll
            for (int g = 0; g < 2; ++g)
                glds16<AUXA>(Abase + aoff[g] + (kt + 1) * 64, &At[cur ^ 1][dstA[g]]);
#pragma unroll
            for (int r = 0; r < 4; ++r)
                glds16<0>(Wt + boff[r] + (kt + 1) * 64, &Bt[cur ^ 1][dstB[r]]);
        }
        mma_tile(At[cur], Bt[cur], l, wr, wc, acc);
        __syncthreads();
    }
}

// ---------------------------------------------------------------------------
// Persistent cooperative LSTM: all 64 steps, one dispatch.
// 256 blocks x 512 threads; LDS 97.5KB -> exactly 1 block/CU -> exactly 32
// blocks per XCD. Each block reads its physical XCC_ID and negotiates a slot:
//   pair = xcc*4 + (slot&3); dir = pair>>4; by = pair&15; bx = slot>>2.
// => the 8 blocks sharing h-tile (by,dir) are PROVABLY on one XCD, and each
// XCD uses exactly one dir's 4MB weight set (L2-resident all 64 steps).
// h moves through the XCD-local L2 only: plain stores (write-through L1),
// cached loads + per-step L1-only invalidate (buffer_inv sc0). No agent
// fences, no L2 invalidate. Only the epoch flag crosses XCDs (atomics).
// ---------------------------------------------------------------------------
__global__ __launch_bounds__(512, 2) void lstm_all(
    const int* __restrict__ in1, const int* __restrict__ in2,
    const int* __restrict__ sl1, const int* __restrict__ sl2,
    const int* __restrict__ perm, const int* __restrict__ Acnt,
    const f16* __restrict__ embH, const f16* __restrict__ Wt,
    const float* __restrict__ bfw, const float* __restrict__ bbw,
    f16* __restrict__ hb0, f16* __restrict__ hb1,
    int* __restrict__ scnt) {
    const int tid = threadIdx.x;
    const int l = tid & 63, w = tid >> 6;

    // ---- role negotiation on the physical XCD
    unsigned xcc;
    asm("s_getreg_b32 %0, hwreg(HW_REG_XCC_ID)" : "=s"(xcc));
    xcc &= 7;
    __shared__ int slot_sh;
    if (tid == 0)
        slot_sh = __hip_atomic_fetch_add(&scnt[160 + (int)xcc], 1,
                                         __ATOMIC_RELAXED,
                                         __HIP_MEMORY_SCOPE_AGENT);
    __syncthreads();
    const int slot = slot_sh;                  // 0..31 within this XCD
    const int pair = (int)xcc * 4 + (slot & 3);
    const int bx   = slot >> 2;                // 0..7 (256-col tile)
    const int dir  = pair >> 4;                // XCDs 0-3: dir0, 4-7: dir1
    const int by   = pair & 15;                // row tile 0..15
    const int grp  = (int)xcc;                 // sync group = XCD (32 blocks)

    __shared__ f16 At[2][8192];      // 32 KB
    __shared__ f16 Bt[2][16384];     // 64 KB
    __shared__ int toks[128];
    __shared__ int slens[128];
    __shared__ int acs[SEQL];

    int myb = 0, mys = 0;
    const int* myinp = in1;
    if (tid < 128) {
        int r = perm[by * 128 + tid];
        myb = r & (BATCH - 1);
        myinp = (r < BATCH) ? in1 : in2;
        mys = (r < BATCH) ? sl1[myb] : sl2[myb];
        slens[tid] = mys;
        int tt0 = dir ? (mys - 1) : 0;          // t=0 active for all (s>=1)
        toks[tid] = myinp[myb * SEQL + tt0];
    }
    if (tid < SEQL) acs[tid] = Acnt[tid];
    __syncthreads();

    // ---- constant staging descriptors
    const int kg8 = (((l & 7) ^ ((l >> 3) & 7))) * 8;
    int dstA[2]; size_t boffX[4], boffH[4]; int dstB[4]; int aoffH[2];
    const size_t habase = (size_t)(dir * ROWS + by * 128) << 9;
#pragma unroll
    for (int g = 0; g < 2; ++g) {
        dstA[g]  = (tid + g * 512) * 8;
        aoffH[g] = (int)(((tid >> 3) + g * 64) * 512 + kg8);
    }
#pragma unroll
    for (int r = 0; r < 4; ++r) {
        int col = (tid >> 3) + r * 64;      // 0..255
        boffX[r] = ((size_t)(dir * 2048 + bx * 256 + col) << 10) + kg8;
        boffH[r] = boffX[r] + 512;
        dstB[r]  = (tid + r * 512) * 8;
    }
    const int wr = w >> 2, wc = w & 3;

    const float* bias = dir ? bbw : bfw;
    const int ci = l & 15;
    const int cell = (bx * 4 + wc) * 16 + ci;   // 0..511
    float bg[4];
#pragma unroll
    for (int g = 0; g < 4; ++g) bg[g] = bias[g * 512 + cell];

    float creg[4][4];
    f32x4 acc[4][4];
#pragma unroll
    for (int i = 0; i < 4; ++i)
#pragma unroll
        for (int j2 = 0; j2 < 4; ++j2) {
            creg[i][j2] = 0.0f;
            acc[i][j2] = (f32x4){0.f, 0.f, 0.f, 0.f};
        }

    // prologue: x-part of t=0 into acc
    {
        int ax[2];
#pragma unroll
        for (int g = 0; g < 2; ++g)
            ax[g] = toks[(tid >> 3) + g * 64] * 512 + kg8;
        gemm512<2>(embH, ax, Wt, boffX, dstA, dstB, l, wr, wc, At, Bt, acc);
    }

#pragma unroll 1
    for (int t = 0; t < SEQL; ++t) {
        const f16* hin = ((t & 1) ? hb1 : hb0) + habase;
        f16* hout      = ((t & 1) ? hb0 : hb1) + habase;
        if (by * 128 < acs[t]) {
            gemm512<0>(hin, aoffH, Wt, boffH, dstA, dstB, l, wr, wc, At, Bt, acc);
            // fused LSTM epilogue: lane owns 1 cell, 16 rows
#pragma unroll
            for (int fm = 0; fm < 4; ++fm) {
#pragma unroll
                for (int reg = 0; reg < 4; ++reg) {
                    int rl = wr * 64 + fm * 16 + (l >> 4) * 4 + reg;
                    float gi = acc[fm][0][reg] + bg[0];
                    float gj = acc[fm][1][reg] + bg[1];
                    float gf = acc[fm][2][reg] + bg[2];
                    float go = acc[fm][3][reg] + bg[3];
                    float cn = creg[fm][reg] * sigf(gf + 1.0f)
                             + sigf(gi) * tanh_fast(gj);
                    float hn = tanh_fast(cn) * sigf(go);
                    f16 hf = (f16)hn;
                    unsigned hv = *(unsigned short*)&hf;
                    unsigned ov = (unsigned)__shfl_xor((int)hv, 1);
                    if (t < slens[rl]) {
                        creg[fm][reg] = cn;
                        if ((l & 1) == 0) {
                            unsigned pk = hv | (ov << 16);
                            // plain store -> lands in this XCD's L2 (the only
                            // readers are on this XCD by construction)
                            *(unsigned*)(hout + ((size_t)rl << 9) + cell) = pk;
                        }
                    }
                }
            }
        }
        if (t < SEQL - 1) {
            __syncthreads();   // each wave drains vmcnt -> h stores in L2
            if (tid == 0) {
                int old = __hip_atomic_fetch_add(&scnt[grp << 4], 1,
                    __ATOMIC_RELAXED, __HIP_MEMORY_SCOPE_AGENT);
                if (old == 32 * (t + 1) - 1) {
                    int m = __hip_atomic_fetch_add(&scnt[128], 1,
                        __ATOMIC_RELAXED, __HIP_MEMORY_SCOPE_AGENT);
                    if (m == 8 * (t + 1) - 1)
                        __hip_atomic_store(&scnt[144], t + 1,
                                           __ATOMIC_RELAXED,
                                           __HIP_MEMORY_SCOPE_AGENT);
                }
            }
            if (tid < 128) {
                int t1 = t + 1;
                int tt = dir ? ((t1 < mys) ? (mys - 1 - t1) : t1) : t1;
                toks[tid] = myinp[myb * SEQL + tt];
            }
#pragma unroll
            for (int i = 0; i < 4; ++i)
#pragma unroll
                for (int j2 = 0; j2 < 4; ++j2)
                    acc[i][j2] = (f32x4){0.f, 0.f, 0.f, 0.f};
            __syncthreads();
            if (by * 128 < acs[t + 1]) {
                int ax[2];
#pragma unroll
                for (int g = 0; g < 2; ++g)
                    ax[g] = toks[(tid >> 3) + g * 64] * 512 + kg8;
                gemm512<2>(embH, ax, Wt, boffX, dstA, dstB, l, wr, wc, At, Bt, acc);
            }
            if (tid == 0) {
                while (__hip_atomic_load(&scnt[144], __ATOMIC_RELAXED,
                                         __HIP_MEMORY_SCOPE_AGENT) < t + 1)
                    __builtin_amdgcn_s_sleep(2);
            }
            __syncthreads();
            // L1-only invalidate: next h-GEMM must not hit stale per-CU L1.
            // (L2 untouched -> weights stay resident.)
            asm volatile("buffer_inv sc0" ::: "memory");
        }
    }
}

// ---------------------------------------------------------------------------
// Build h_combined fp16 [1024][3136]; final h of row r in buf[s&1], row inv[r].
// ---------------------------------------------------------------------------
__global__ __launch_bounds__(256) void build_hc(const f16* __restrict__ hbuf0,
                                                const f16* __restrict__ hbuf1,
                                                const int* __restrict__ sl1,
                                                const int* __restrict__ sl2,
                                                const int* __restrict__ inv,
                                                f16* __restrict__ hc) {
    int b = blockIdx.x;
    int tid = threadIdx.x;
    __shared__ float red[256];
    int s1 = sl1[b], s2 = sl2[b];
    int p1 = inv[b], p2 = inv[BATCH + b];
    const f16* hf1 = (s1 & 1) ? hbuf1 : hbuf0;
    const f16* hf2 = (s2 & 1) ? hbuf1 : hbuf0;
    float d = 0.0f;
    size_t base = (size_t)b * HC_K;
    for (int k = tid; k < 1024; k += 256) {
        int dir = k >> 9, kk = k & 511;
        float h1 = (float)hf1[((size_t)(dir * ROWS + p1) << 9) + kk];
        float h2 = (float)hf2[((size_t)(dir * ROWS + p2) << 9) + kk];
        hc[base + k]        = (f16)h1;
        hc[base + 1024 + k] = (f16)h2;
        hc[base + 2049 + k] = (f16)(h1 * h2);
        float df = h1 - h2;
        d += df * df;
    }
    red[tid] = d;
    __syncthreads();
    for (int s = 128; s > 0; s >>= 1) {
        if (tid < s) red[tid] += red[tid + s];
        __syncthreads();
    }
    if (tid == 0) hc[base + 2048] = (f16)red[0];
    if (tid < HC_K - 3073) hc[base + 3073 + tid] = (f16)0.0f;
}

// ---------------------------------------------------------------------------
// e1 = relu(hc @ W1 + b1)  fp16 MFMA 64x64 tile, BK=64, dbuf
// ---------------------------------------------------------------------------
__global__ __launch_bounds__(256) void mlp1(const f16* __restrict__ hc,
                                            const f16* __restrict__ W1t,
                                            const float* __restrict__ b1,
                                            float* __restrict__ e1) {
    const int bx = blockIdx.x, by = blockIdx.y, tid = threadIdx.x;
    const int l = tid & 63, w = tid >> 6;
    __shared__ f16 Atile[2][64 * 64];
    __shared__ f16 Btile[2][64 * 64];

    const int kg8 = (((l & 7) ^ ((l >> 3) & 7))) * 8;
    size_t aoff[2], boff[2]; int dst[2];
#pragma unroll
    for (int g = 0; g < 2; ++g) {
        int row = g * 32 + w * 8 + (l >> 3);
        aoff[g] = (size_t)(by * 64 + row) * HC_K + kg8;
        boff[g] = (size_t)(bx * 64 + row) * HC_K + kg8;
        dst[g]  = (g * 32 + w * 8) * 64;
    }

    f32x4 acc[2][2];
#pragma unroll
    for (int i = 0; i < 2; ++i)
#pragma unroll
        for (int j = 0; j < 2; ++j) acc[i][j] = (f32x4){0.f, 0.f, 0.f, 0.f};

    const int wr = w >> 1, wc = w & 1;

#pragma unroll
    for (int g = 0; g < 2; ++g) {
        glds16<0>(hc + aoff[g], &Atile[0][dst[g]]);
        glds16<0>(W1t + boff[g], &Btile[0][dst[g]]);
    }
    __syncthreads();

    int cur = 0;
    for (int kt = 0; kt < HC_K / 64; ++kt) {
        if (kt < HC_K / 64 - 1) {
            const int kn = (kt + 1) * 64;
#pragma unroll
            for (int g = 0; g < 2; ++g) {
                glds16<0>(hc + aoff[g] + kn, &Atile[cur ^ 1][dst[g]]);
                glds16<0>(W1t + boff[g] + kn, &Btile[cur ^ 1][dst[g]]);
            }
        }
#pragma unroll
        for (int kk = 0; kk < 2; ++kk) {
            f16x8 af[2], bv[2];
            const int slot = (l >> 4) + kk * 4;
#pragma unroll
            for (int fm = 0; fm < 2; ++fm) {
                int row = wr * 32 + fm * 16 + (l & 15);
                af[fm] = *(const f16x8*)&Atile[cur][row * 64 + (slot ^ (row & 7)) * 8];
            }
#pragma unroll
            for (int fn = 0; fn < 2; ++fn) {
                int col = wc * 32 + fn * 16 + (l & 15);
                bv[fn] = *(const f16x8*)&Btile[cur][col * 64 + (slot ^ (col & 7)) * 8];
            }
#pragma unroll
            for (int fm = 0; fm < 2; ++fm)
#pragma unroll
                for (int fn = 0; fn < 2; ++fn)
                    acc[fm][fn] = __builtin_amdgcn_mfma_f32_16x16x32_f16(
                        af[fm], bv[fn], acc[fm][fn], 0, 0, 0);
        }
        __syncthreads();
        cur ^= 1;
    }

#pragma unroll
    for (int fm = 0; fm < 2; ++fm) {
#pragma unroll
        for (int fn = 0; fn < 2; ++fn) {
#pragma unroll
            for (int reg = 0; reg < 4; ++reg) {
                int r = by * 64 + wr * 32 + fm * 16 + (l >> 4) * 4 + reg;
                int c = bx * 64 + wc * 32 + fn * 16 + (l & 15);
                float v = acc[fm][fn][reg] + b1[c];
                e1[(size_t)r * MDIM + c] = v > 0.0f ? v : 0.0f;
            }
        }
    }
}

// ---------------------------------------------------------------------------
// preds = e1 @ W2 + b2
// ---------------------------------------------------------------------------
__global__ __launch_bounds__(64) void mlp2(const float* __restrict__ e1,
                                           const float* __restrict__ W2,
                                           const float* __restrict__ b2,
                                           float* __restrict__ out) {
    int b = blockIdx.x, tid = threadIdx.x;
    float p0 = 0.f, p1 = 0.f;
    for (int k = tid; k < 512; k += 64) {
        float e = e1[(size_t)b * MDIM + k];
        p0 += e * W2[2 * k];
        p1 += e * W2[2 * k + 1];
    }
    for (int off = 32; off > 0; off >>= 1) {
        p0 += __shfl_down(p0, off);
        p1 += __shfl_down(p1, off);
    }
    if (tid == 0) {
        out[2 * b]     = p0 + b2[0];
        out[2 * b + 1] = p1 + b2[1];
    }
}

// ---------------------------------------------------------------------------
extern "C" void kernel_launch(void* const* d_in, const int* in_sizes, int n_in,
                              void* d_out, int out_size, void* d_ws, size_t ws_size,
                              hipStream_t stream) {
    (void)in_sizes; (void)n_in; (void)out_size; (void)ws_size;
    const int*   in1 = (const int*)d_in[0];
    const int*   in2 = (const int*)d_in[1];
    const int*   sl1 = (const int*)d_in[2];
    const int*   sl2 = (const int*)d_in[3];
    const float* emb = (const float*)d_in[4];
    const float* kfw = (const float*)d_in[5];
    const float* bfw = (const float*)d_in[6];
    const float* kbw = (const float*)d_in[7];
    const float* bbw = (const float*)d_in[8];
    const float* W1  = (const float*)d_in[9];
    const float* b1  = (const float*)d_in[10];
    const float* W2  = (const float*)d_in[11];
    const float* b2  = (const float*)d_in[12];
    float* out = (float*)d_out;

    char* base = (char*)d_ws;
    f16*   embH = (f16*)base;                      // 51,200,000 B
    f16*   Wt   = (f16*)(base + 51200000);         //  8,388,608 B
    f16*   W1t  = (f16*)(base + 59588608);         //  3,211,264 B
    f16*   h0   = (f16*)(base + 62799872);         //  4,194,304 B
    f16*   h1   = (f16*)(base + 66994176);         //  4,194,304 B
    f16*   hc   = (f16*)(base + 71188480);         //  6,422,528 B
    float* e1   = (float*)(base + 77611008);       //  2,097,152 B
    int*   perm = (int*)(base + 79708160);         //      8,192 B
    int*   inv  = (int*)(base + 79716352);         //      8,192 B
    int*   Acnt = (int*)(base + 79724544);         //        256 B
    int*   sync = (int*)(base + 79724800);         //      1,024 B

    hipMemsetAsync(h0, 0, 4194304, stream);        // h state at t=0
    hipMemsetAsync(sync, 0, 1024, stream);         // epoch + slot counters

    sort_rows<<<ROWS / 256, 256, 0, stream>>>(sl1, sl2, perm, inv, Acnt);
    conv_emb<<<(VOCAB * D_EMB / 8 + 255) / 256, 256, 0, stream>>>(emb, embH, VOCAB * D_EMB / 8);
    pack_w<<<(2 * 2048 * 1024) / 256, 256, 0, stream>>>(kfw, kbw, Wt);
    pack_w1<<<(512 * HC_K + 255) / 256, 256, 0, stream>>>(W1, W1t);

    {
        const f16* embH_c = embH;
        const f16* Wt_c   = Wt;
        const int* perm_c = perm;
        const int* Acnt_c = Acnt;
        f16* h0_p = h0;
        f16* h1_p = h1;
        int* sync_p = sync;
        void* ka[] = {
            (void*)&in1, (void*)&in2, (void*)&sl1, (void*)&sl2,
            (void*)&perm_c, (void*)&Acnt_c, (void*)&embH_c, (void*)&Wt_c,
            (void*)&bfw, (void*)&bbw, (void*)&h0_p, (void*)&h1_p, (void*)&sync_p
        };
        hipLaunchCooperativeKernel((const void*)lstm_all, dim3(NBLK), dim3(512),
                                   ka, 0, stream);
    }

    build_hc<<<BATCH, 256, 0, stream>>>(h0, h1, sl1, sl2, inv, hc);
    mlp1<<<dim3(MDIM / 64, BATCH / 64), 256, 0, stream>>>(hc, W1t, b1, e1);
    mlp2<<<BATCH, 64, 0, stream>>>(e1, W2, b2, out);
}